// Round 1
// baseline (1058.538 us; speedup 1.0000x reference)
//
#include <hip/hip_runtime.h>
#include <math.h>

#define NEG_SLOPE 0.2f

// ---------------- CSR construction ----------------

__global__ void k_zero(int* __restrict__ p, int n) {
    int i = blockIdx.x * blockDim.x + threadIdx.x;
    if (i < n) p[i] = 0;
}

__global__ void k_count(const int* __restrict__ dst, int E, int* __restrict__ counts) {
    int e = blockIdx.x * blockDim.x + threadIdx.x;
    if (e < E) atomicAdd(&counts[dst[e]], 1);
}

// Single-block exclusive scan over N counts -> offsets[N+1]; also seeds cursor.
__global__ __launch_bounds__(1024) void k_scan(const int* __restrict__ counts,
                                               int* __restrict__ offsets,
                                               int* __restrict__ cursor, int N) {
    __shared__ int part[1024];
    int t = threadIdx.x;
    int chunk = (N + 1023) >> 10;
    int lo = t * chunk;
    int hi = lo + chunk; if (hi > N) hi = N; if (lo > N) lo = N;
    int s = 0;
    for (int i = lo; i < hi; ++i) s += counts[i];
    part[t] = s;
    __syncthreads();
    for (int off = 1; off < 1024; off <<= 1) {
        int v = (t >= off) ? part[t - off] : 0;
        __syncthreads();
        part[t] += v;
        __syncthreads();
    }
    int base = (t == 0) ? 0 : part[t - 1];
    for (int i = lo; i < hi; ++i) {
        offsets[i] = base;
        cursor[i] = base;
        base += counts[i];
    }
    if (t == 1023) offsets[N] = part[1023];
}

__global__ void k_scatter(const int* __restrict__ src, const int* __restrict__ dst, int E,
                          int* __restrict__ cursor, int* __restrict__ csr_src) {
    int e = blockIdx.x * blockDim.x + threadIdx.x;
    if (e < E) {
        int d = dst[e];
        int pos = atomicAdd(&cursor[d], 1);
        csr_src[pos] = src[e];
    }
}

// ---------------- Layer 1: h1 = x @ W1 (+ attention logits) ----------------
// One wave per node; lane j owns output channel j (64 channels = 8 heads x 8).
__global__ __launch_bounds__(256) void k_gemm1(const float* __restrict__ x,
                                               const float* __restrict__ W1,
                                               const float* __restrict__ att_s,
                                               const float* __restrict__ att_d,
                                               float* __restrict__ h1,
                                               float* __restrict__ a_s1,
                                               float* __restrict__ a_d1, int N) {
    __shared__ float wlds[128 * 64];
    __shared__ float xlds[4 * 128];
    int tid = threadIdx.x;
    const float4* w4 = (const float4*)W1;
    float4* wl4 = (float4*)wlds;
    for (int i = tid; i < 128 * 64 / 4; i += 256) wl4[i] = w4[i];
    int wave = tid >> 6, lane = tid & 63;
    int n = blockIdx.x * 4 + wave;
    if (n < N) {
        xlds[wave * 128 + lane]      = x[(size_t)n * 128 + lane];
        xlds[wave * 128 + 64 + lane] = x[(size_t)n * 128 + 64 + lane];
    }
    __syncthreads();
    if (n >= N) return;
    float acc = 0.f;
    const float* xr = &xlds[wave * 128];
#pragma unroll 16
    for (int k = 0; k < 128; ++k) acc = fmaf(xr[k], wlds[k * 64 + lane], acc);
    h1[(size_t)n * 64 + lane] = acc;
    // a_src[n,h] = sum_c h[n,h,c]*att_src[h,c]; lane j = h*8+c -> reduce over 8-lane groups
    float ps = acc * att_s[lane];
    float pd = acc * att_d[lane];
#pragma unroll
    for (int m = 1; m < 8; m <<= 1) {
        ps += __shfl_xor(ps, m, 64);
        pd += __shfl_xor(pd, m, 64);
    }
    if ((lane & 7) == 0) {
        a_s1[n * 8 + (lane >> 3)] = ps;
        a_d1[n * 8 + (lane >> 3)] = pd;
    }
}

// ---------------- Layer 1 aggregation (gather per dst node) + bias + ELU ----------------
__global__ __launch_bounds__(256) void k_agg1(const float* __restrict__ h1,
                                              const float* __restrict__ a_s1,
                                              const float* __restrict__ a_d1,
                                              const int* __restrict__ offsets,
                                              const int* __restrict__ csr_src,
                                              const float* __restrict__ b1,
                                              float* __restrict__ y1, int N) {
    int wave = threadIdx.x >> 6, lane = threadIdx.x & 63;
    int d = blockIdx.x * 4 + wave;
    if (d >= N) return;
    int h = lane >> 3;
    float ad = a_d1[d * 8 + h];
    // self-loop term
    float e0 = a_s1[d * 8 + h] + ad;
    e0 = e0 > 0.f ? e0 : NEG_SLOPE * e0;
    float w0 = __expf(e0);
    float acc = w0 * h1[(size_t)d * 64 + lane];
    float wsum = w0;
    int i0 = offsets[d], i1 = offsets[d + 1];
    for (int i = i0; i < i1; ++i) {
        int s = csr_src[i];
        float e = a_s1[s * 8 + h] + ad;
        e = e > 0.f ? e : NEG_SLOPE * e;
        float w = __expf(e);
        acc = fmaf(w, h1[(size_t)s * 64 + lane], acc);
        wsum += w;
    }
    float o = acc / (wsum + 1e-16f) + b1[lane];
    y1[(size_t)d * 64 + lane] = o > 0.f ? o : expm1f(o);  // ELU
}

// ---------------- Layer 2: h2 = y1 @ W2 (+ attention logits) ----------------
__global__ __launch_bounds__(256) void k_gemm2(const float* __restrict__ y1,
                                               const float* __restrict__ W2,
                                               const float* __restrict__ att_s,
                                               const float* __restrict__ att_d,
                                               float* __restrict__ h2,
                                               float* __restrict__ a2s,
                                               float* __restrict__ a2d, int N) {
    __shared__ float wlds[64 * 40];
    __shared__ float xlds[4 * 64];
    int tid = threadIdx.x;
    for (int i = tid; i < 64 * 40; i += 256) wlds[i] = W2[i];
    int wave = tid >> 6, lane = tid & 63;
    int n = blockIdx.x * 4 + wave;
    if (n < N) xlds[wave * 64 + lane] = y1[(size_t)n * 64 + lane];
    __syncthreads();
    if (n >= N) return;
    float acc = 0.f;
    if (lane < 40) {
        const float* xr = &xlds[wave * 64];
#pragma unroll 8
        for (int k = 0; k < 64; ++k) acc = fmaf(xr[k], wlds[k * 40 + lane], acc);
        h2[(size_t)n * 40 + lane] = acc;
    }
    float ps = (lane < 40) ? acc * att_s[lane] : 0.f;
    float pd = (lane < 40) ? acc * att_d[lane] : 0.f;
#pragma unroll
    for (int m = 1; m < 64; m <<= 1) {
        ps += __shfl_xor(ps, m, 64);
        pd += __shfl_xor(pd, m, 64);
    }
    if (lane == 0) {
        a2s[n] = ps;
        a2d[n] = pd;
    }
}

// ---------------- Layer 2 aggregation + bias + log_softmax ----------------
__global__ __launch_bounds__(256) void k_agg2(const float* __restrict__ h2,
                                              const float* __restrict__ a2s,
                                              const float* __restrict__ a2d,
                                              const int* __restrict__ offsets,
                                              const int* __restrict__ csr_src,
                                              const float* __restrict__ b2,
                                              float* __restrict__ out, int N) {
    int wave = threadIdx.x >> 6, lane = threadIdx.x & 63;
    int d = blockIdx.x * 4 + wave;
    if (d >= N) return;
    float ad = a2d[d];
    float e0 = a2s[d] + ad;
    e0 = e0 > 0.f ? e0 : NEG_SLOPE * e0;
    float w0 = __expf(e0);
    float acc = (lane < 40) ? w0 * h2[(size_t)d * 40 + lane] : 0.f;
    float wsum = w0;
    int i0 = offsets[d], i1 = offsets[d + 1];
    for (int i = i0; i < i1; ++i) {
        int s = csr_src[i];
        float e = a2s[s] + ad;
        e = e > 0.f ? e : NEG_SLOPE * e;
        float w = __expf(e);
        if (lane < 40) acc = fmaf(w, h2[(size_t)s * 40 + lane], acc);
        wsum += w;
    }
    float o = (lane < 40) ? (acc / (wsum + 1e-16f) + b2[lane]) : -INFINITY;
    // log_softmax over the 40 active lanes
    float m = o;
#pragma unroll
    for (int mm = 1; mm < 64; mm <<= 1) m = fmaxf(m, __shfl_xor(m, mm, 64));
    float ex = (lane < 40) ? __expf(o - m) : 0.f;
#pragma unroll
    for (int mm = 1; mm < 64; mm <<= 1) ex += __shfl_xor(ex, mm, 64);
    if (lane < 40) out[(size_t)d * 40 + lane] = o - m - __logf(ex);
}

// ---------------- launcher ----------------

extern "C" void kernel_launch(void* const* d_in, const int* in_sizes, int n_in,
                              void* d_out, int out_size, void* d_ws, size_t ws_size,
                              hipStream_t stream) {
    const float* x   = (const float*)d_in[0];
    const int*   ei  = (const int*)d_in[1];
    const float* W1  = (const float*)d_in[2];
    const float* as1 = (const float*)d_in[3];
    const float* ad1 = (const float*)d_in[4];
    const float* b1  = (const float*)d_in[5];
    const float* W2  = (const float*)d_in[6];
    const float* as2 = (const float*)d_in[7];
    const float* ad2 = (const float*)d_in[8];
    const float* b2  = (const float*)d_in[9];
    float* out = (float*)d_out;

    int N = in_sizes[0] / 128;   // 100000
    int E = in_sizes[1] / 2;     // 1600000
    const int* src = ei;
    const int* dst = ei + E;

    char* ws = (char*)d_ws;
    size_t off = 0;
    auto alloc = [&](size_t bytes) -> char* {
        char* p = ws + off;
        off += (bytes + 255) & ~(size_t)255;
        return p;
    };
    float* h1      = (float*)alloc((size_t)N * 64 * 4);
    float* a_s1    = (float*)alloc((size_t)N * 8 * 4);
    float* a_d1    = (float*)alloc((size_t)N * 8 * 4);
    float* y1      = (float*)alloc((size_t)N * 64 * 4);
    float* h2      = (float*)alloc((size_t)N * 40 * 4);
    float* a2s     = (float*)alloc((size_t)N * 4);
    float* a2d     = (float*)alloc((size_t)N * 4);
    int*   counts  = (int*)alloc((size_t)N * 4);
    int*   offsets = (int*)alloc((size_t)(N + 1) * 4);
    int*   cursor  = (int*)alloc((size_t)N * 4);
    int*   csr_src = (int*)alloc((size_t)E * 4);

    int nb = (N + 3) / 4;
    k_zero<<<(N + 255) / 256, 256, 0, stream>>>(counts, N);
    k_count<<<(E + 255) / 256, 256, 0, stream>>>(dst, E, counts);
    k_scan<<<1, 1024, 0, stream>>>(counts, offsets, cursor, N);
    k_scatter<<<(E + 255) / 256, 256, 0, stream>>>(src, dst, E, cursor, csr_src);
    k_gemm1<<<nb, 256, 0, stream>>>(x, W1, as1, ad1, h1, a_s1, a_d1, N);
    k_agg1<<<nb, 256, 0, stream>>>(h1, a_s1, a_d1, offsets, csr_src, b1, y1, N);
    k_gemm2<<<nb, 256, 0, stream>>>(y1, W2, as2, ad2, h2, a2s, a2d, N);
    k_agg2<<<nb, 256, 0, stream>>>(h2, a2s, a2d, offsets, csr_src, b2, out, N);
}

// Round 2
// 842.310 us; speedup vs baseline: 1.2567x; 1.2567x over previous
//
#include <hip/hip_runtime.h>
#include <math.h>

#define NEG_SLOPE 0.2f

// ---------------- CSR construction ----------------

__global__ void k_zero(int* __restrict__ p, int n) {
    int i = blockIdx.x * blockDim.x + threadIdx.x;
    if (i < n) p[i] = 0;
}

__global__ void k_count(const int* __restrict__ dst, int E, int* __restrict__ counts) {
    int e = blockIdx.x * blockDim.x + threadIdx.x;
    if (e < E) atomicAdd(&counts[dst[e]], 1);
}

// ---- 3-phase device-wide exclusive scan over counts[N] -> offsets[N+1] ----
// Phase 1: per-block (256-wide) exclusive scan + block sums.
__global__ __launch_bounds__(256) void k_presum(const int* __restrict__ counts,
                                                int* __restrict__ offsets,
                                                int* __restrict__ bsum, int N) {
    int t = threadIdx.x;
    int i = blockIdx.x * 256 + t;
    int v = (i < N) ? counts[i] : 0;
    int lane = t & 63, wv = t >> 6;
    int s = v;
#pragma unroll
    for (int o = 1; o < 64; o <<= 1) {
        int u = __shfl_up(s, o, 64);
        if (lane >= o) s += u;
    }
    __shared__ int wsum[4];
    if (lane == 63) wsum[wv] = s;
    __syncthreads();
    int base = 0;
#pragma unroll
    for (int w = 0; w < 4; ++w) base += (w < wv) ? wsum[w] : 0;
    int incl = s + base;
    if (i < N) offsets[i] = incl - v;          // local exclusive prefix
    if (t == 255) bsum[blockIdx.x] = incl;     // block total
}

// Phase 2: single small block scans the ~391 block sums -> exclusive bpre[NB+1].
__global__ __launch_bounds__(512) void k_scan_bsums(const int* __restrict__ bsum,
                                                    int* __restrict__ bpre, int NB) {
    __shared__ int sh[512];
    int t = threadIdx.x;
    int v = (t < NB) ? bsum[t] : 0;
    sh[t] = v;
    __syncthreads();
#pragma unroll
    for (int o = 1; o < 512; o <<= 1) {
        int u = (t >= o) ? sh[t - o] : 0;
        __syncthreads();
        sh[t] += u;
        __syncthreads();
    }
    if (t < NB) bpre[t] = sh[t] - v;
    if (t == NB - 1) bpre[NB] = sh[t];
}

// Phase 3: add block base, seed cursor, write total at offsets[N].
__global__ __launch_bounds__(256) void k_addbase(int* __restrict__ offsets,
                                                 int* __restrict__ cursor,
                                                 const int* __restrict__ bpre,
                                                 int N, int NB) {
    int b = blockIdx.x;
    int i = b * 256 + threadIdx.x;
    if (i < N) {
        int off = offsets[i] + bpre[b];
        offsets[i] = off;
        cursor[i] = off;
    }
    if (i == 0) offsets[N] = bpre[NB];
}

__global__ void k_scatter(const int* __restrict__ src, const int* __restrict__ dst, int E,
                          int* __restrict__ cursor, int* __restrict__ csr_src) {
    int e = blockIdx.x * blockDim.x + threadIdx.x;
    if (e < E) {
        int d = dst[e];
        int pos = atomicAdd(&cursor[d], 1);
        csr_src[pos] = src[e];
    }
}

// ---------------- Layer 1: h1 = x @ W1 (+ attention logits) ----------------
__global__ __launch_bounds__(256) void k_gemm1(const float* __restrict__ x,
                                               const float* __restrict__ W1,
                                               const float* __restrict__ att_s,
                                               const float* __restrict__ att_d,
                                               float* __restrict__ h1,
                                               float* __restrict__ a_s1,
                                               float* __restrict__ a_d1, int N) {
    __shared__ float wlds[128 * 64];
    __shared__ float xlds[4 * 128];
    int tid = threadIdx.x;
    const float4* w4 = (const float4*)W1;
    float4* wl4 = (float4*)wlds;
    for (int i = tid; i < 128 * 64 / 4; i += 256) wl4[i] = w4[i];
    int wave = tid >> 6, lane = tid & 63;
    int n = blockIdx.x * 4 + wave;
    if (n < N) {
        xlds[wave * 128 + lane]      = x[(size_t)n * 128 + lane];
        xlds[wave * 128 + 64 + lane] = x[(size_t)n * 128 + 64 + lane];
    }
    __syncthreads();
    if (n >= N) return;
    float acc = 0.f;
    const float* xr = &xlds[wave * 128];
#pragma unroll 16
    for (int k = 0; k < 128; ++k) acc = fmaf(xr[k], wlds[k * 64 + lane], acc);
    h1[(size_t)n * 64 + lane] = acc;
    float ps = acc * att_s[lane];
    float pd = acc * att_d[lane];
#pragma unroll
    for (int m = 1; m < 8; m <<= 1) {
        ps += __shfl_xor(ps, m, 64);
        pd += __shfl_xor(pd, m, 64);
    }
    if ((lane & 7) == 0) {
        a_s1[n * 8 + (lane >> 3)] = ps;
        a_d1[n * 8 + (lane >> 3)] = pd;
    }
}

// ---------------- Layer 1 aggregation (gather per dst node) + bias + ELU ----------------
__global__ __launch_bounds__(256) void k_agg1(const float* __restrict__ h1,
                                              const float* __restrict__ a_s1,
                                              const float* __restrict__ a_d1,
                                              const int* __restrict__ offsets,
                                              const int* __restrict__ csr_src,
                                              const float* __restrict__ b1,
                                              float* __restrict__ y1, int N) {
    int wave = threadIdx.x >> 6, lane = threadIdx.x & 63;
    int d = blockIdx.x * 4 + wave;
    if (d >= N) return;
    int h = lane >> 3;
    float ad = a_d1[d * 8 + h];
    float e0 = a_s1[d * 8 + h] + ad;
    e0 = e0 > 0.f ? e0 : NEG_SLOPE * e0;
    float w0 = __expf(e0);
    float acc = w0 * h1[(size_t)d * 64 + lane];
    float wsum = w0;
    int i0 = offsets[d], i1 = offsets[d + 1];
    for (int i = i0; i < i1; ++i) {
        int s = csr_src[i];
        float e = a_s1[s * 8 + h] + ad;
        e = e > 0.f ? e : NEG_SLOPE * e;
        float w = __expf(e);
        acc = fmaf(w, h1[(size_t)s * 64 + lane], acc);
        wsum += w;
    }
    float o = acc / (wsum + 1e-16f) + b1[lane];
    y1[(size_t)d * 64 + lane] = o > 0.f ? o : expm1f(o);  // ELU
}

// ---------------- Layer 2: h2 = y1 @ W2 (+ attention logits) ----------------
__global__ __launch_bounds__(256) void k_gemm2(const float* __restrict__ y1,
                                               const float* __restrict__ W2,
                                               const float* __restrict__ att_s,
                                               const float* __restrict__ att_d,
                                               float* __restrict__ h2,
                                               float* __restrict__ a2s,
                                               float* __restrict__ a2d, int N) {
    __shared__ float wlds[64 * 40];
    __shared__ float xlds[4 * 64];
    int tid = threadIdx.x;
    for (int i = tid; i < 64 * 40; i += 256) wlds[i] = W2[i];
    int wave = tid >> 6, lane = tid & 63;
    int n = blockIdx.x * 4 + wave;
    if (n < N) xlds[wave * 64 + lane] = y1[(size_t)n * 64 + lane];
    __syncthreads();
    if (n >= N) return;
    float acc = 0.f;
    if (lane < 40) {
        const float* xr = &xlds[wave * 64];
#pragma unroll 8
        for (int k = 0; k < 64; ++k) acc = fmaf(xr[k], wlds[k * 40 + lane], acc);
        h2[(size_t)n * 40 + lane] = acc;
    }
    float ps = (lane < 40) ? acc * att_s[lane] : 0.f;
    float pd = (lane < 40) ? acc * att_d[lane] : 0.f;
#pragma unroll
    for (int m = 1; m < 64; m <<= 1) {
        ps += __shfl_xor(ps, m, 64);
        pd += __shfl_xor(pd, m, 64);
    }
    if (lane == 0) {
        a2s[n] = ps;
        a2d[n] = pd;
    }
}

// ---------------- Layer 2 aggregation + bias + log_softmax ----------------
__global__ __launch_bounds__(256) void k_agg2(const float* __restrict__ h2,
                                              const float* __restrict__ a2s,
                                              const float* __restrict__ a2d,
                                              const int* __restrict__ offsets,
                                              const int* __restrict__ csr_src,
                                              const float* __restrict__ b2,
                                              float* __restrict__ out, int N) {
    int wave = threadIdx.x >> 6, lane = threadIdx.x & 63;
    int d = blockIdx.x * 4 + wave;
    if (d >= N) return;
    float ad = a2d[d];
    float e0 = a2s[d] + ad;
    e0 = e0 > 0.f ? e0 : NEG_SLOPE * e0;
    float w0 = __expf(e0);
    float acc = (lane < 40) ? w0 * h2[(size_t)d * 40 + lane] : 0.f;
    float wsum = w0;
    int i0 = offsets[d], i1 = offsets[d + 1];
    for (int i = i0; i < i1; ++i) {
        int s = csr_src[i];
        float e = a2s[s] + ad;
        e = e > 0.f ? e : NEG_SLOPE * e;
        float w = __expf(e);
        if (lane < 40) acc = fmaf(w, h2[(size_t)s * 40 + lane], acc);
        wsum += w;
    }
    float o = (lane < 40) ? (acc / (wsum + 1e-16f) + b2[lane]) : -INFINITY;
    float m = o;
#pragma unroll
    for (int mm = 1; mm < 64; mm <<= 1) m = fmaxf(m, __shfl_xor(m, mm, 64));
    float ex = (lane < 40) ? __expf(o - m) : 0.f;
#pragma unroll
    for (int mm = 1; mm < 64; mm <<= 1) ex += __shfl_xor(ex, mm, 64);
    if (lane < 40) out[(size_t)d * 40 + lane] = o - m - __logf(ex);
}

// ---------------- launcher ----------------

extern "C" void kernel_launch(void* const* d_in, const int* in_sizes, int n_in,
                              void* d_out, int out_size, void* d_ws, size_t ws_size,
                              hipStream_t stream) {
    const float* x   = (const float*)d_in[0];
    const int*   ei  = (const int*)d_in[1];
    const float* W1  = (const float*)d_in[2];
    const float* as1 = (const float*)d_in[3];
    const float* ad1 = (const float*)d_in[4];
    const float* b1  = (const float*)d_in[5];
    const float* W2  = (const float*)d_in[6];
    const float* as2 = (const float*)d_in[7];
    const float* ad2 = (const float*)d_in[8];
    const float* b2  = (const float*)d_in[9];
    float* out = (float*)d_out;

    int N = in_sizes[0] / 128;   // 100000
    int E = in_sizes[1] / 2;     // 1600000
    const int* src = ei;
    const int* dst = ei + E;

    char* ws = (char*)d_ws;
    size_t off = 0;
    auto alloc = [&](size_t bytes) -> char* {
        char* p = ws + off;
        off += (bytes + 255) & ~(size_t)255;
        return p;
    };
    float* h1      = (float*)alloc((size_t)N * 64 * 4);
    float* a_s1    = (float*)alloc((size_t)N * 8 * 4);
    float* a_d1    = (float*)alloc((size_t)N * 8 * 4);
    float* y1      = (float*)alloc((size_t)N * 64 * 4);
    float* h2      = (float*)alloc((size_t)N * 40 * 4);
    float* a2s     = (float*)alloc((size_t)N * 4);
    float* a2d     = (float*)alloc((size_t)N * 4);
    int*   counts  = (int*)alloc((size_t)N * 4);
    int*   offsets = (int*)alloc((size_t)(N + 1) * 4);
    int*   cursor  = (int*)alloc((size_t)N * 4);
    int*   csr_src = (int*)alloc((size_t)E * 4);
    int NB = (N + 255) / 256;    // 391
    int*   bsum    = (int*)alloc((size_t)NB * 4);
    int*   bpre    = (int*)alloc((size_t)(NB + 1) * 4);

    int nb = (N + 3) / 4;
    k_zero<<<(N + 255) / 256, 256, 0, stream>>>(counts, N);
    k_count<<<(E + 255) / 256, 256, 0, stream>>>(dst, E, counts);
    k_presum<<<NB, 256, 0, stream>>>(counts, offsets, bsum, N);
    k_scan_bsums<<<1, 512, 0, stream>>>(bsum, bpre, NB);
    k_addbase<<<NB, 256, 0, stream>>>(offsets, cursor, bpre, N, NB);
    k_scatter<<<(E + 255) / 256, 256, 0, stream>>>(src, dst, E, cursor, csr_src);
    k_gemm1<<<nb, 256, 0, stream>>>(x, W1, as1, ad1, h1, a_s1, a_d1, N);
    k_agg1<<<nb, 256, 0, stream>>>(h1, a_s1, a_d1, offsets, csr_src, b1, y1, N);
    k_gemm2<<<nb, 256, 0, stream>>>(y1, W2, as2, ad2, h2, a2s, a2d, N);
    k_agg2<<<nb, 256, 0, stream>>>(h2, a2s, a2d, offsets, csr_src, b2, out, N);
}

// Round 3
// 814.909 us; speedup vs baseline: 1.2990x; 1.0336x over previous
//
#include <hip/hip_runtime.h>
#include <math.h>

#define NEG_SLOPE 0.2f

static __device__ __forceinline__ float lrelu_exp(float e) {
    e = e > 0.f ? e : NEG_SLOPE * e;
    return __expf(e);
}

// ---------------- CSR construction ----------------

__global__ void k_zero(int* __restrict__ p, int n) {
    int i = blockIdx.x * blockDim.x + threadIdx.x;
    if (i < n) p[i] = 0;
}

__global__ void k_count(const int* __restrict__ dst, int E, int* __restrict__ counts) {
    int e = blockIdx.x * blockDim.x + threadIdx.x;
    if (e < E) atomicAdd(&counts[dst[e]], 1);
}

// Phase 1: per-block (256-wide) exclusive scan + block sums.
__global__ __launch_bounds__(256) void k_presum(const int* __restrict__ counts,
                                                int* __restrict__ offsets,
                                                int* __restrict__ bsum, int N) {
    int t = threadIdx.x;
    int i = blockIdx.x * 256 + t;
    int v = (i < N) ? counts[i] : 0;
    int lane = t & 63, wv = t >> 6;
    int s = v;
#pragma unroll
    for (int o = 1; o < 64; o <<= 1) {
        int u = __shfl_up(s, o, 64);
        if (lane >= o) s += u;
    }
    __shared__ int wsum[4];
    if (lane == 63) wsum[wv] = s;
    __syncthreads();
    int base = 0;
#pragma unroll
    for (int w = 0; w < 4; ++w) base += (w < wv) ? wsum[w] : 0;
    int incl = s + base;
    if (i < N) offsets[i] = incl - v;
    if (t == 255) bsum[blockIdx.x] = incl;
}

// Phase 2: single block scans the ~391 block sums.
__global__ __launch_bounds__(512) void k_scan_bsums(const int* __restrict__ bsum,
                                                    int* __restrict__ bpre, int NB) {
    __shared__ int sh[512];
    int t = threadIdx.x;
    int v = (t < NB) ? bsum[t] : 0;
    sh[t] = v;
    __syncthreads();
#pragma unroll
    for (int o = 1; o < 512; o <<= 1) {
        int u = (t >= o) ? sh[t - o] : 0;
        __syncthreads();
        sh[t] += u;
        __syncthreads();
    }
    if (t < NB) bpre[t] = sh[t] - v;
    if (t == NB - 1) bpre[NB] = sh[t];
}

// Phase 3: add block base, seed cursor, write total.
__global__ __launch_bounds__(256) void k_addbase(int* __restrict__ offsets,
                                                 int* __restrict__ cursor,
                                                 const int* __restrict__ bpre,
                                                 int N, int NB) {
    int b = blockIdx.x;
    int i = b * 256 + threadIdx.x;
    if (i < N) {
        int off = offsets[i] + bpre[b];
        offsets[i] = off;
        cursor[i] = off;
    }
    if (i == 0) offsets[N] = bpre[NB];
}

__global__ void k_scatter(const int* __restrict__ src, const int* __restrict__ dst, int E,
                          int* __restrict__ cursor, int* __restrict__ csr_src) {
    int e = blockIdx.x * blockDim.x + threadIdx.x;
    if (e < E) {
        int d = dst[e];
        int pos = atomicAdd(&cursor[d], 1);
        csr_src[pos] = src[e];
    }
}

// ---------------- Layer 1: h1 = x @ W1 (+ attention logits), grid-stride ----------------
// W1 staged in LDS ONCE per block; wave per node; x row held in 2 regs, broadcast by shfl.
__global__ __launch_bounds__(256) void k_gemm1(const float* __restrict__ x,
                                               const float* __restrict__ W1,
                                               const float* __restrict__ att_s,
                                               const float* __restrict__ att_d,
                                               float* __restrict__ h1,
                                               float* __restrict__ a_s1,
                                               float* __restrict__ a_d1, int N) {
    __shared__ float wlds[128 * 64];
    int tid = threadIdx.x;
    const float4* w4 = (const float4*)W1;
    float4* wl4 = (float4*)wlds;
    for (int i = tid; i < 128 * 64 / 4; i += 256) wl4[i] = w4[i];
    __syncthreads();
    int wave = tid >> 6, lane = tid & 63;
    float ats = att_s[lane], atd = att_d[lane];
    for (int n = blockIdx.x * 4 + wave; n < N; n += gridDim.x * 4) {
        float xv0 = x[(size_t)n * 128 + lane];
        float xv1 = x[(size_t)n * 128 + 64 + lane];
        float acc = 0.f;
#pragma unroll
        for (int k = 0; k < 64; ++k)
            acc = fmaf(__shfl(xv0, k, 64), wlds[k * 64 + lane], acc);
#pragma unroll
        for (int k = 0; k < 64; ++k)
            acc = fmaf(__shfl(xv1, k, 64), wlds[(64 + k) * 64 + lane], acc);
        h1[(size_t)n * 64 + lane] = acc;
        float ps = acc * ats, pd = acc * atd;
#pragma unroll
        for (int m = 1; m < 8; m <<= 1) {
            ps += __shfl_xor(ps, m, 64);
            pd += __shfl_xor(pd, m, 64);
        }
        if ((lane & 7) == 0) {
            a_s1[n * 8 + (lane >> 3)] = ps;
            a_d1[n * 8 + (lane >> 3)] = pd;
        }
    }
}

// ---------------- Layer 1 aggregation: chunked src prefetch + unroll-4 gathers ----------------
__global__ __launch_bounds__(256) void k_agg1(const float* __restrict__ h1,
                                              const float* __restrict__ a_s1,
                                              const float* __restrict__ a_d1,
                                              const int* __restrict__ offsets,
                                              const int* __restrict__ csr_src,
                                              const float* __restrict__ b1,
                                              float* __restrict__ y1, int N) {
    int wave = threadIdx.x >> 6, lane = threadIdx.x & 63;
    int d = blockIdx.x * 4 + wave;
    if (d >= N) return;
    int h = lane >> 3;
    float ad = a_d1[d * 8 + h];
    float w0 = lrelu_exp(a_s1[d * 8 + h] + ad);
    float acc = w0 * h1[(size_t)d * 64 + lane];
    float wsum = w0;
    int i0 = offsets[d], i1 = offsets[d + 1];
    for (int base = i0; base < i1; base += 64) {
        int m = i1 - base; if (m > 64) m = 64;
        int sv = (lane < m) ? csr_src[base + lane] : 0;   // one coalesced load for 64 edges
        int j = 0;
        for (; j + 4 <= m; j += 4) {
            int s0 = __shfl(sv, j, 64), s1 = __shfl(sv, j + 1, 64),
                s2 = __shfl(sv, j + 2, 64), s3 = __shfl(sv, j + 3, 64);
            float a0 = a_s1[s0 * 8 + h], a1 = a_s1[s1 * 8 + h],
                  a2 = a_s1[s2 * 8 + h], a3 = a_s1[s3 * 8 + h];
            float v0 = h1[(size_t)s0 * 64 + lane], v1 = h1[(size_t)s1 * 64 + lane],
                  v2 = h1[(size_t)s2 * 64 + lane], v3 = h1[(size_t)s3 * 64 + lane];
            float w;
            w = lrelu_exp(a0 + ad); acc = fmaf(w, v0, acc); wsum += w;
            w = lrelu_exp(a1 + ad); acc = fmaf(w, v1, acc); wsum += w;
            w = lrelu_exp(a2 + ad); acc = fmaf(w, v2, acc); wsum += w;
            w = lrelu_exp(a3 + ad); acc = fmaf(w, v3, acc); wsum += w;
        }
        for (; j < m; ++j) {
            int s = __shfl(sv, j, 64);
            float w = lrelu_exp(a_s1[s * 8 + h] + ad);
            acc = fmaf(w, h1[(size_t)s * 64 + lane], acc);
            wsum += w;
        }
    }
    float o = acc / (wsum + 1e-16f) + b1[lane];
    y1[(size_t)d * 64 + lane] = o > 0.f ? o : expm1f(o);  // ELU
}

// ---------------- Layer 2: h2 = y1 @ W2 (+ attention logits), grid-stride ----------------
__global__ __launch_bounds__(256) void k_gemm2(const float* __restrict__ y1,
                                               const float* __restrict__ W2,
                                               const float* __restrict__ att_s,
                                               const float* __restrict__ att_d,
                                               float* __restrict__ h2,
                                               float* __restrict__ a2s,
                                               float* __restrict__ a2d, int N) {
    __shared__ float wlds[64 * 40 + 24];   // +24 pad so lanes 40..63 read in-bounds garbage
    int tid = threadIdx.x;
    for (int i = tid; i < 64 * 40 + 24; i += 256) wlds[i] = (i < 64 * 40) ? W2[i] : 0.f;
    __syncthreads();
    int wave = tid >> 6, lane = tid & 63;
    float ats = (lane < 40) ? att_s[lane] : 0.f;
    float atd = (lane < 40) ? att_d[lane] : 0.f;
    for (int n = blockIdx.x * 4 + wave; n < N; n += gridDim.x * 4) {
        float yv = y1[(size_t)n * 64 + lane];
        float acc = 0.f;
#pragma unroll
        for (int k = 0; k < 64; ++k)
            acc = fmaf(__shfl(yv, k, 64), wlds[k * 40 + lane], acc);
        if (lane < 40) h2[(size_t)n * 40 + lane] = acc;
        float ps = (lane < 40) ? acc * ats : 0.f;
        float pd = (lane < 40) ? acc * atd : 0.f;
#pragma unroll
        for (int m = 1; m < 64; m <<= 1) {
            ps += __shfl_xor(ps, m, 64);
            pd += __shfl_xor(pd, m, 64);
        }
        if (lane == 0) { a2s[n] = ps; a2d[n] = pd; }
    }
}

// ---------------- Layer 2 aggregation: lane-parallel weights + unroll-4 gathers ----------------
__global__ __launch_bounds__(256) void k_agg2(const float* __restrict__ h2,
                                              const float* __restrict__ a2s,
                                              const float* __restrict__ a2d,
                                              const int* __restrict__ offsets,
                                              const int* __restrict__ csr_src,
                                              const float* __restrict__ b2,
                                              float* __restrict__ out, int N) {
    int wave = threadIdx.x >> 6, lane = threadIdx.x & 63;
    int d = blockIdx.x * 4 + wave;
    if (d >= N) return;
    float ad = a2d[d];
    float w0 = lrelu_exp(a2s[d] + ad);
    float acc = (lane < 40) ? w0 * h2[(size_t)d * 40 + lane] : 0.f;
    float wsum_l = 0.f;
    int i0 = offsets[d], i1 = offsets[d + 1];
    for (int base = i0; base < i1; base += 64) {
        int m = i1 - base; if (m > 64) m = 64;
        int sv = 0; float wv = 0.f;
        if (lane < m) {
            sv = csr_src[base + lane];              // one coalesced load for 64 edges
            wv = lrelu_exp(a2s[sv] + ad);           // all 64 edge weights in parallel
        }
        wsum_l += wv;
        int j = 0;
        for (; j + 4 <= m; j += 4) {
            int s0 = __shfl(sv, j, 64), s1 = __shfl(sv, j + 1, 64),
                s2 = __shfl(sv, j + 2, 64), s3 = __shfl(sv, j + 3, 64);
            float wq0 = __shfl(wv, j, 64), wq1 = __shfl(wv, j + 1, 64),
                  wq2 = __shfl(wv, j + 2, 64), wq3 = __shfl(wv, j + 3, 64);
            if (lane < 40) {
                float v0 = h2[(size_t)s0 * 40 + lane], v1 = h2[(size_t)s1 * 40 + lane],
                      v2 = h2[(size_t)s2 * 40 + lane], v3 = h2[(size_t)s3 * 40 + lane];
                acc = fmaf(wq0, v0, acc); acc = fmaf(wq1, v1, acc);
                acc = fmaf(wq2, v2, acc); acc = fmaf(wq3, v3, acc);
            }
        }
        for (; j < m; ++j) {
            int s = __shfl(sv, j, 64);
            float wq = __shfl(wv, j, 64);
            if (lane < 40) acc = fmaf(wq, h2[(size_t)s * 40 + lane], acc);
        }
    }
#pragma unroll
    for (int mm = 1; mm < 64; mm <<= 1) wsum_l += __shfl_xor(wsum_l, mm, 64);
    float wsum = wsum_l + w0;
    float o = (lane < 40) ? (acc / (wsum + 1e-16f) + b2[lane]) : -INFINITY;
    float mx = o;
#pragma unroll
    for (int mm = 1; mm < 64; mm <<= 1) mx = fmaxf(mx, __shfl_xor(mx, mm, 64));
    float ex = (lane < 40) ? __expf(o - mx) : 0.f;
#pragma unroll
    for (int mm = 1; mm < 64; mm <<= 1) ex += __shfl_xor(ex, mm, 64);
    if (lane < 40) out[(size_t)d * 40 + lane] = o - mx - __logf(ex);
}

// ---------------- launcher ----------------

extern "C" void kernel_launch(void* const* d_in, const int* in_sizes, int n_in,
                              void* d_out, int out_size, void* d_ws, size_t ws_size,
                              hipStream_t stream) {
    const float* x   = (const float*)d_in[0];
    const int*   ei  = (const int*)d_in[1];
    const float* W1  = (const float*)d_in[2];
    const float* as1 = (const float*)d_in[3];
    const float* ad1 = (const float*)d_in[4];
    const float* b1  = (const float*)d_in[5];
    const float* W2  = (const float*)d_in[6];
    const float* as2 = (const float*)d_in[7];
    const float* ad2 = (const float*)d_in[8];
    const float* b2  = (const float*)d_in[9];
    float* out = (float*)d_out;

    int N = in_sizes[0] / 128;   // 100000
    int E = in_sizes[1] / 2;     // 1600000
    const int* src = ei;
    const int* dst = ei + E;

    char* ws = (char*)d_ws;
    size_t off = 0;
    auto alloc = [&](size_t bytes) -> char* {
        char* p = ws + off;
        off += (bytes + 255) & ~(size_t)255;
        return p;
    };
    float* h1      = (float*)alloc((size_t)N * 64 * 4);
    float* a_s1    = (float*)alloc((size_t)N * 8 * 4);
    float* a_d1    = (float*)alloc((size_t)N * 8 * 4);
    float* y1      = (float*)alloc((size_t)N * 64 * 4);
    float* h2      = (float*)alloc((size_t)N * 40 * 4);
    float* a2s     = (float*)alloc((size_t)N * 4);
    float* a2d     = (float*)alloc((size_t)N * 4);
    int*   counts  = (int*)alloc((size_t)N * 4);
    int*   offsets = (int*)alloc((size_t)(N + 1) * 4);
    int*   cursor  = (int*)alloc((size_t)N * 4);
    int*   csr_src = (int*)alloc((size_t)E * 4);
    int NB = (N + 255) / 256;    // 391
    int*   bsum    = (int*)alloc((size_t)NB * 4);
    int*   bpre    = (int*)alloc((size_t)(NB + 1) * 4);

    int nb = (N + 3) / 4;
    k_zero<<<(N + 255) / 256, 256, 0, stream>>>(counts, N);
    k_count<<<(E + 255) / 256, 256, 0, stream>>>(dst, E, counts);
    k_presum<<<NB, 256, 0, stream>>>(counts, offsets, bsum, N);
    k_scan_bsums<<<1, 512, 0, stream>>>(bsum, bpre, NB);
    k_addbase<<<NB, 256, 0, stream>>>(offsets, cursor, bpre, N, NB);
    k_scatter<<<(E + 255) / 256, 256, 0, stream>>>(src, dst, E, cursor, csr_src);
    k_gemm1<<<392, 256, 0, stream>>>(x, W1, as1, ad1, h1, a_s1, a_d1, N);
    k_agg1<<<nb, 256, 0, stream>>>(h1, a_s1, a_d1, offsets, csr_src, b1, y1, N);
    k_gemm2<<<392, 256, 0, stream>>>(y1, W2, as2, ad2, h2, a2s, a2d, N);
    k_agg2<<<nb, 256, 0, stream>>>(h2, a2s, a2d, offsets, csr_src, b2, out, N);
}

// Round 4
// 502.027 us; speedup vs baseline: 2.1085x; 1.6232x over previous
//
#include <hip/hip_runtime.h>
#include <math.h>

#define NEG_SLOPE 0.2f

typedef __attribute__((ext_vector_type(8))) short short8;   // 8 bf16 (MFMA A/B frag)
typedef __attribute__((ext_vector_type(4))) float floatx4;  // MFMA C/D frag

static __device__ __forceinline__ float lrelu_exp(float e) {
    e = e > 0.f ? e : NEG_SLOPE * e;
    return __expf(e);
}

// fp32 -> bf16 (round-to-nearest-even)
static __device__ __forceinline__ short f2bf(float f) {
    union { float f; unsigned u; } v; v.f = f;
    unsigned r = v.u + 0x7FFFu + ((v.u >> 16) & 1u);
    return (short)(r >> 16);
}

// ---------------- CSR construction ----------------

__global__ void k_zero(int* __restrict__ p, int n) {
    int i = blockIdx.x * blockDim.x + threadIdx.x;
    if (i < n) p[i] = 0;
}

__global__ void k_count(const int* __restrict__ dst, int E, int* __restrict__ counts) {
    int e = blockIdx.x * blockDim.x + threadIdx.x;
    if (e < E) atomicAdd(&counts[dst[e]], 1);
}

__global__ __launch_bounds__(256) void k_presum(const int* __restrict__ counts,
                                                int* __restrict__ offsets,
                                                int* __restrict__ bsum, int N) {
    int t = threadIdx.x;
    int i = blockIdx.x * 256 + t;
    int v = (i < N) ? counts[i] : 0;
    int lane = t & 63, wv = t >> 6;
    int s = v;
#pragma unroll
    for (int o = 1; o < 64; o <<= 1) {
        int u = __shfl_up(s, o, 64);
        if (lane >= o) s += u;
    }
    __shared__ int wsum[4];
    if (lane == 63) wsum[wv] = s;
    __syncthreads();
    int base = 0;
#pragma unroll
    for (int w = 0; w < 4; ++w) base += (w < wv) ? wsum[w] : 0;
    int incl = s + base;
    if (i < N) offsets[i] = incl - v;
    if (t == 255) bsum[blockIdx.x] = incl;
}

__global__ __launch_bounds__(512) void k_scan_bsums(const int* __restrict__ bsum,
                                                    int* __restrict__ bpre, int NB) {
    __shared__ int sh[512];
    int t = threadIdx.x;
    int v = (t < NB) ? bsum[t] : 0;
    sh[t] = v;
    __syncthreads();
#pragma unroll
    for (int o = 1; o < 512; o <<= 1) {
        int u = (t >= o) ? sh[t - o] : 0;
        __syncthreads();
        sh[t] += u;
        __syncthreads();
    }
    if (t < NB) bpre[t] = sh[t] - v;
    if (t == NB - 1) bpre[NB] = sh[t];
}

__global__ __launch_bounds__(256) void k_addbase(int* __restrict__ offsets,
                                                 int* __restrict__ cursor,
                                                 const int* __restrict__ bpre,
                                                 int N, int NB) {
    int b = blockIdx.x;
    int i = b * 256 + threadIdx.x;
    if (i < N) {
        int off = offsets[i] + bpre[b];
        offsets[i] = off;
        cursor[i] = off;
    }
    if (i == 0) offsets[N] = bpre[NB];
}

__global__ void k_scatter(const int* __restrict__ src, const int* __restrict__ dst, int E,
                          int* __restrict__ cursor, int* __restrict__ csr_src) {
    int e = blockIdx.x * blockDim.x + threadIdx.x;
    if (e < E) {
        int d = dst[e];
        int pos = atomicAdd(&cursor[d], 1);
        csr_src[pos] = src[e];
    }
}

// ---------------- Layer 1 GEMM via MFMA bf16: h1[N,64] = x[N,128] @ W1[128,64] ----------------
// One wave = 16 rows. B (W1) held in registers (16 frags), A loaded+cvt from global.
// Layouts (verified, guide §3): A[m=lane&15][k=(lane>>4)*8+j]; B[n=lane&15][k=(lane>>4)*8+j];
// C/D: col=lane&15, row=(lane>>4)*4+reg.
__global__ __launch_bounds__(256) void k_gemm1(const float* __restrict__ x,
                                               const float* __restrict__ W1,
                                               const float* __restrict__ att_s,
                                               const float* __restrict__ att_d,
                                               float* __restrict__ h1,
                                               float* __restrict__ a_s1,
                                               float* __restrict__ a_d1, int N) {
    int tid = threadIdx.x, wave = tid >> 6, lane = tid & 63;
    int n16 = lane & 15, q = lane >> 4;
    int nb = blockIdx.x * 64 + wave * 16;
    if (nb >= N) return;

    // B fragments: frag(ct,kc): n = ct*16+n16, k = kc*32 + q*8 + j ; B[k][n] = W1[k*64+n]
    short8 bfr[4][4];
#pragma unroll
    for (int ct = 0; ct < 4; ++ct) {
        int n = ct * 16 + n16;
#pragma unroll
        for (int kc = 0; kc < 4; ++kc) {
            int k0 = kc * 32 + q * 8;
            short8 b;
#pragma unroll
            for (int j = 0; j < 8; ++j) b[j] = f2bf(W1[(k0 + j) * 64 + n]);
            bfr[ct][kc] = b;
        }
    }

    // A fragments: row nb+n16 (clamped), k = kc*32 + q*8 + j
    int arow = nb + n16; if (arow >= N) arow = N - 1;
    const float* xr = x + (size_t)arow * 128 + q * 8;
    short8 afr[4];
#pragma unroll
    for (int kc = 0; kc < 4; ++kc) {
        float4 u0 = *(const float4*)(xr + kc * 32);
        float4 u1 = *(const float4*)(xr + kc * 32 + 4);
        short8 a;
        a[0] = f2bf(u0.x); a[1] = f2bf(u0.y); a[2] = f2bf(u0.z); a[3] = f2bf(u0.w);
        a[4] = f2bf(u1.x); a[5] = f2bf(u1.y); a[6] = f2bf(u1.z); a[7] = f2bf(u1.w);
        afr[kc] = a;
    }

    floatx4 acc[4];
#pragma unroll
    for (int ct = 0; ct < 4; ++ct) {
        floatx4 c = {0.f, 0.f, 0.f, 0.f};
#pragma unroll
        for (int kc = 0; kc < 4; ++kc)
            c = __builtin_amdgcn_mfma_f32_16x16x32_bf16(afr[kc], bfr[ct][kc], c, 0, 0, 0);
        acc[ct] = c;
    }

    // store h1: row = nb + q*4 + r, col = ct*16 + n16
#pragma unroll
    for (int ct = 0; ct < 4; ++ct) {
#pragma unroll
        for (int r = 0; r < 4; ++r) {
            int row = nb + q * 4 + r;
            if (row < N) h1[(size_t)row * 64 + ct * 16 + n16] = acc[ct][r];
        }
    }

    // attention logits: head h covers cols [8h,8h+8); col = ct*16+n16 -> h = 2ct + (n16>>3)
#pragma unroll
    for (int ct = 0; ct < 4; ++ct) {
        float as = att_s[ct * 16 + n16];
        float ad = att_d[ct * 16 + n16];
#pragma unroll
        for (int r = 0; r < 4; ++r) {
            float ps = acc[ct][r] * as;
            float pd = acc[ct][r] * ad;
#pragma unroll
            for (int m = 1; m < 8; m <<= 1) {
                ps += __shfl_xor(ps, m, 64);
                pd += __shfl_xor(pd, m, 64);
            }
            int row = nb + q * 4 + r;
            if ((n16 & 7) == 0 && row < N) {
                int h = 2 * ct + (n16 >> 3);
                a_s1[row * 8 + h] = ps;
                a_d1[row * 8 + h] = pd;
            }
        }
    }
}

// ---------------- Layer 1 aggregation (unchanged from R3) ----------------
__global__ __launch_bounds__(256) void k_agg1(const float* __restrict__ h1,
                                              const float* __restrict__ a_s1,
                                              const float* __restrict__ a_d1,
                                              const int* __restrict__ offsets,
                                              const int* __restrict__ csr_src,
                                              const float* __restrict__ b1,
                                              float* __restrict__ y1, int N) {
    int wave = threadIdx.x >> 6, lane = threadIdx.x & 63;
    int d = blockIdx.x * 4 + wave;
    if (d >= N) return;
    int h = lane >> 3;
    float ad = a_d1[d * 8 + h];
    float w0 = lrelu_exp(a_s1[d * 8 + h] + ad);
    float acc = w0 * h1[(size_t)d * 64 + lane];
    float wsum = w0;
    int i0 = offsets[d], i1 = offsets[d + 1];
    for (int base = i0; base < i1; base += 64) {
        int m = i1 - base; if (m > 64) m = 64;
        int sv = (lane < m) ? csr_src[base + lane] : 0;
        int j = 0;
        for (; j + 4 <= m; j += 4) {
            int s0 = __shfl(sv, j, 64), s1 = __shfl(sv, j + 1, 64),
                s2 = __shfl(sv, j + 2, 64), s3 = __shfl(sv, j + 3, 64);
            float a0 = a_s1[s0 * 8 + h], a1 = a_s1[s1 * 8 + h],
                  a2 = a_s1[s2 * 8 + h], a3 = a_s1[s3 * 8 + h];
            float v0 = h1[(size_t)s0 * 64 + lane], v1 = h1[(size_t)s1 * 64 + lane],
                  v2 = h1[(size_t)s2 * 64 + lane], v3 = h1[(size_t)s3 * 64 + lane];
            float w;
            w = lrelu_exp(a0 + ad); acc = fmaf(w, v0, acc); wsum += w;
            w = lrelu_exp(a1 + ad); acc = fmaf(w, v1, acc); wsum += w;
            w = lrelu_exp(a2 + ad); acc = fmaf(w, v2, acc); wsum += w;
            w = lrelu_exp(a3 + ad); acc = fmaf(w, v3, acc); wsum += w;
        }
        for (; j < m; ++j) {
            int s = __shfl(sv, j, 64);
            float w = lrelu_exp(a_s1[s * 8 + h] + ad);
            acc = fmaf(w, h1[(size_t)s * 64 + lane], acc);
            wsum += w;
        }
    }
    float o = acc / (wsum + 1e-16f) + b1[lane];
    y1[(size_t)d * 64 + lane] = o > 0.f ? o : expm1f(o);  // ELU
}

// ---------------- Layer 2 GEMM via MFMA bf16: h2[N,40] = y1[N,64] @ W2[64,40] ----------------
// N padded 40->48 (3 col-tiles); cols 40..47 of B are zero.
__global__ __launch_bounds__(256) void k_gemm2(const float* __restrict__ y1,
                                               const float* __restrict__ W2,
                                               const float* __restrict__ att_s,
                                               const float* __restrict__ att_d,
                                               float* __restrict__ h2,
                                               float* __restrict__ a2s,
                                               float* __restrict__ a2d, int N) {
    int tid = threadIdx.x, wave = tid >> 6, lane = tid & 63;
    int n16 = lane & 15, q = lane >> 4;
    int nb = blockIdx.x * 64 + wave * 16;
    if (nb >= N) return;

    short8 bfr[3][2];
#pragma unroll
    for (int ct = 0; ct < 3; ++ct) {
        int n = ct * 16 + n16;
#pragma unroll
        for (int kc = 0; kc < 2; ++kc) {
            int k0 = kc * 32 + q * 8;
            short8 b;
#pragma unroll
            for (int j = 0; j < 8; ++j)
                b[j] = (n < 40) ? f2bf(W2[(k0 + j) * 40 + n]) : (short)0;
            bfr[ct][kc] = b;
        }
    }

    int arow = nb + n16; if (arow >= N) arow = N - 1;
    const float* yr = y1 + (size_t)arow * 64 + q * 8;
    short8 afr[2];
#pragma unroll
    for (int kc = 0; kc < 2; ++kc) {
        float4 u0 = *(const float4*)(yr + kc * 32);
        float4 u1 = *(const float4*)(yr + kc * 32 + 4);
        short8 a;
        a[0] = f2bf(u0.x); a[1] = f2bf(u0.y); a[2] = f2bf(u0.z); a[3] = f2bf(u0.w);
        a[4] = f2bf(u1.x); a[5] = f2bf(u1.y); a[6] = f2bf(u1.z); a[7] = f2bf(u1.w);
        afr[kc] = a;
    }

    floatx4 acc[3];
#pragma unroll
    for (int ct = 0; ct < 3; ++ct) {
        floatx4 c = {0.f, 0.f, 0.f, 0.f};
        c = __builtin_amdgcn_mfma_f32_16x16x32_bf16(afr[0], bfr[ct][0], c, 0, 0, 0);
        c = __builtin_amdgcn_mfma_f32_16x16x32_bf16(afr[1], bfr[ct][1], c, 0, 0, 0);
        acc[ct] = c;
    }

#pragma unroll
    for (int ct = 0; ct < 3; ++ct) {
        int col = ct * 16 + n16;
#pragma unroll
        for (int r = 0; r < 4; ++r) {
            int row = nb + q * 4 + r;
            if (col < 40 && row < N) h2[(size_t)row * 40 + col] = acc[ct][r];
        }
    }

    // single-head logits: reduce cols across ct in-lane, then over 16 lanes (n16)
#pragma unroll
    for (int r = 0; r < 4; ++r) {
        float ps = 0.f, pd = 0.f;
#pragma unroll
        for (int ct = 0; ct < 3; ++ct) {
            int col = ct * 16 + n16;
            float asv = (col < 40) ? att_s[col] : 0.f;
            float adv = (col < 40) ? att_d[col] : 0.f;
            ps = fmaf(acc[ct][r], asv, ps);
            pd = fmaf(acc[ct][r], adv, pd);
        }
#pragma unroll
        for (int m = 1; m < 16; m <<= 1) {
            ps += __shfl_xor(ps, m, 64);
            pd += __shfl_xor(pd, m, 64);
        }
        int row = nb + q * 4 + r;
        if (n16 == 0 && row < N) { a2s[row] = ps; a2d[row] = pd; }
    }
}

// ---------------- Layer 2 aggregation (unchanged from R3) ----------------
__global__ __launch_bounds__(256) void k_agg2(const float* __restrict__ h2,
                                              const float* __restrict__ a2s,
                                              const float* __restrict__ a2d,
                                              const int* __restrict__ offsets,
                                              const int* __restrict__ csr_src,
                                              const float* __restrict__ b2,
                                              float* __restrict__ out, int N) {
    int wave = threadIdx.x >> 6, lane = threadIdx.x & 63;
    int d = blockIdx.x * 4 + wave;
    if (d >= N) return;
    float ad = a2d[d];
    float w0 = lrelu_exp(a2s[d] + ad);
    float acc = (lane < 40) ? w0 * h2[(size_t)d * 40 + lane] : 0.f;
    float wsum_l = 0.f;
    int i0 = offsets[d], i1 = offsets[d + 1];
    for (int base = i0; base < i1; base += 64) {
        int m = i1 - base; if (m > 64) m = 64;
        int sv = 0; float wv = 0.f;
        if (lane < m) {
            sv = csr_src[base + lane];
            wv = lrelu_exp(a2s[sv] + ad);
        }
        wsum_l += wv;
        int j = 0;
        for (; j + 4 <= m; j += 4) {
            int s0 = __shfl(sv, j, 64), s1 = __shfl(sv, j + 1, 64),
                s2 = __shfl(sv, j + 2, 64), s3 = __shfl(sv, j + 3, 64);
            float wq0 = __shfl(wv, j, 64), wq1 = __shfl(wv, j + 1, 64),
                  wq2 = __shfl(wv, j + 2, 64), wq3 = __shfl(wv, j + 3, 64);
            if (lane < 40) {
                float v0 = h2[(size_t)s0 * 40 + lane], v1 = h2[(size_t)s1 * 40 + lane],
                      v2 = h2[(size_t)s2 * 40 + lane], v3 = h2[(size_t)s3 * 40 + lane];
                acc = fmaf(wq0, v0, acc); acc = fmaf(wq1, v1, acc);
                acc = fmaf(wq2, v2, acc); acc = fmaf(wq3, v3, acc);
            }
        }
        for (; j < m; ++j) {
            int s = __shfl(sv, j, 64);
            float wq = __shfl(wv, j, 64);
            if (lane < 40) acc = fmaf(wq, h2[(size_t)s * 40 + lane], acc);
        }
    }
#pragma unroll
    for (int mm = 1; mm < 64; mm <<= 1) wsum_l += __shfl_xor(wsum_l, mm, 64);
    float wsum = wsum_l + w0;
    float o = (lane < 40) ? (acc / (wsum + 1e-16f) + b2[lane]) : -INFINITY;
    float mx = o;
#pragma unroll
    for (int mm = 1; mm < 64; mm <<= 1) mx = fmaxf(mx, __shfl_xor(mx, mm, 64));
    float ex = (lane < 40) ? __expf(o - mx) : 0.f;
#pragma unroll
    for (int mm = 1; mm < 64; mm <<= 1) ex += __shfl_xor(ex, mm, 64);
    if (lane < 40) out[(size_t)d * 40 + lane] = o - mx - __logf(ex);
}

// ---------------- launcher ----------------

extern "C" void kernel_launch(void* const* d_in, const int* in_sizes, int n_in,
                              void* d_out, int out_size, void* d_ws, size_t ws_size,
                              hipStream_t stream) {
    const float* x   = (const float*)d_in[0];
    const int*   ei  = (const int*)d_in[1];
    const float* W1  = (const float*)d_in[2];
    const float* as1 = (const float*)d_in[3];
    const float* ad1 = (const float*)d_in[4];
    const float* b1  = (const float*)d_in[5];
    const float* W2  = (const float*)d_in[6];
    const float* as2 = (const float*)d_in[7];
    const float* ad2 = (const float*)d_in[8];
    const float* b2  = (const float*)d_in[9];
    float* out = (float*)d_out;

    int N = in_sizes[0] / 128;   // 100000
    int E = in_sizes[1] / 2;     // 1600000
    const int* src = ei;
    const int* dst = ei + E;

    char* ws = (char*)d_ws;
    size_t off = 0;
    auto alloc = [&](size_t bytes) -> char* {
        char* p = ws + off;
        off += (bytes + 255) & ~(size_t)255;
        return p;
    };
    float* h1      = (float*)alloc((size_t)N * 64 * 4);
    float* a_s1    = (float*)alloc((size_t)N * 8 * 4);
    float* a_d1    = (float*)alloc((size_t)N * 8 * 4);
    float* y1      = (float*)alloc((size_t)N * 64 * 4);
    float* h2      = (float*)alloc((size_t)N * 40 * 4);
    float* a2s     = (float*)alloc((size_t)N * 4);
    float* a2d     = (float*)alloc((size_t)N * 4);
    int*   counts  = (int*)alloc((size_t)N * 4);
    int*   offsets = (int*)alloc((size_t)(N + 1) * 4);
    int*   cursor  = (int*)alloc((size_t)N * 4);
    int*   csr_src = (int*)alloc((size_t)E * 4);
    int NB = (N + 255) / 256;    // 391
    int*   bsum    = (int*)alloc((size_t)NB * 4);
    int*   bpre    = (int*)alloc((size_t)(NB + 1) * 4);

    int nb = (N + 3) / 4;
    int gb = (N + 63) / 64;      // 1563 blocks for the MFMA GEMMs
    k_zero<<<(N + 255) / 256, 256, 0, stream>>>(counts, N);
    k_count<<<(E + 255) / 256, 256, 0, stream>>>(dst, E, counts);
    k_presum<<<NB, 256, 0, stream>>>(counts, offsets, bsum, N);
    k_scan_bsums<<<1, 512, 0, stream>>>(bsum, bpre, NB);
    k_addbase<<<NB, 256, 0, stream>>>(offsets, cursor, bpre, N, NB);
    k_scatter<<<(E + 255) / 256, 256, 0, stream>>>(src, dst, E, cursor, csr_src);
    k_gemm1<<<gb, 256, 0, stream>>>(x, W1, as1, ad1, h1, a_s1, a_d1, N);
    k_agg1<<<nb, 256, 0, stream>>>(h1, a_s1, a_d1, offsets, csr_src, b1, y1, N);
    k_gemm2<<<gb, 256, 0, stream>>>(y1, W2, as2, ad2, h2, a2s, a2d, N);
    k_agg2<<<nb, 256, 0, stream>>>(h2, a2s, a2d, offsets, csr_src, b2, out, N);
}

// Round 7
// 374.675 us; speedup vs baseline: 2.8252x; 1.3399x over previous
//
#include <hip/hip_runtime.h>
#include <math.h>

#define NEG_SLOPE 0.2f
#define BSHIFT 8            // 256 nodes per bucket
#define MAXBUK 512          // supports N up to 131072

typedef __attribute__((ext_vector_type(8))) short short8;   // 8 bf16 (MFMA A/B frag)
typedef __attribute__((ext_vector_type(4))) float floatx4;  // MFMA C/D frag

static __device__ __forceinline__ float lrelu_exp(float e) {
    e = e > 0.f ? e : NEG_SLOPE * e;
    return __expf(e);
}

// fp32 -> bf16 (round-to-nearest-even)
static __device__ __forceinline__ short f2bf(float f) {
    union { float f; unsigned u; } v; v.f = f;
    unsigned r = v.u + 0x7FFFu + ((v.u >> 16) & 1u);
    return (short)(r >> 16);
}
// bf16 -> fp32 (exact)
static __device__ __forceinline__ float bf2f(short s) {
    union { float f; unsigned u; } v;
    v.u = ((unsigned)(unsigned short)s) << 16;
    return v.f;
}
// split f into hi+lo bf16 pair (covers ~16 mantissa bits)
static __device__ __forceinline__ void splitbf(float f, short& hi, short& lo) {
    hi = f2bf(f);
    lo = f2bf(f - bf2f(hi));
}

// ================= CSR build: LDS-bucketed partition (no global data atomics) =================

__global__ __launch_bounds__(256) void k_hist(const int* __restrict__ dst, int E, int CHUNK,
                                              int NBLK, int NBUK, int* __restrict__ blockhist) {
    __shared__ int hist[MAXBUK];
    int t = threadIdx.x, b = blockIdx.x;
    for (int i = t; i < NBUK; i += 256) hist[i] = 0;
    __syncthreads();
    int e0 = b * CHUNK, e1 = e0 + CHUNK; if (e1 > E) e1 = E;
    for (int e = e0 + t; e < e1; e += 256) atomicAdd(&hist[dst[e] >> BSHIFT], 1);
    __syncthreads();
    for (int i = t; i < NBUK; i += 256) blockhist[i * NBLK + b] = hist[i];
}

__global__ __launch_bounds__(512) void k_bucket_scan(const int* __restrict__ blockhist,
                                                     int* __restrict__ bucketbase,
                                                     int NBLK, int NBUK) {
    __shared__ int sh[512];
    int t = threadIdx.x;
    int tot = 0;
    if (t < NBUK) {
        const int* p = blockhist + (size_t)t * NBLK;
        for (int k = 0; k < NBLK; ++k) tot += p[k];
    }
    sh[t] = tot;
    __syncthreads();
#pragma unroll
    for (int o = 1; o < 512; o <<= 1) {
        int u = (t >= o) ? sh[t - o] : 0;
        __syncthreads();
        sh[t] += u;
        __syncthreads();
    }
    if (t < NBUK) bucketbase[t] = sh[t] - tot;
    if (t == NBUK - 1) bucketbase[NBUK] = sh[t];
}

__global__ __launch_bounds__(256) void k_colscan(int* __restrict__ blockhist,
                                                 const int* __restrict__ bucketbase,
                                                 int NBLK) {
    int bucket = blockIdx.x, t = threadIdx.x;
    int v = (t < NBLK) ? blockhist[(size_t)bucket * NBLK + t] : 0;
    int lane = t & 63, wv = t >> 6;
    int s = v;
#pragma unroll
    for (int o = 1; o < 64; o <<= 1) {
        int u = __shfl_up(s, o, 64);
        if (lane >= o) s += u;
    }
    __shared__ int wsum[4];
    if (lane == 63) wsum[wv] = s;
    __syncthreads();
    int base = 0;
#pragma unroll
    for (int w = 0; w < 4; ++w) base += (w < wv) ? wsum[w] : 0;
    int excl = s + base - v + bucketbase[bucket];
    if (t < NBLK) blockhist[(size_t)bucket * NBLK + t] = excl;
}

__global__ __launch_bounds__(256) void k_partition(const int* __restrict__ src,
                                                   const int* __restrict__ dst, int E, int CHUNK,
                                                   int NBLK, int NBUK,
                                                   const int* __restrict__ blockhist,
                                                   uint2* __restrict__ packed) {
    __shared__ int cur[MAXBUK];
    int t = threadIdx.x, b = blockIdx.x;
    for (int i = t; i < NBUK; i += 256) cur[i] = blockhist[(size_t)i * NBLK + b];
    __syncthreads();
    int e0 = b * CHUNK, e1 = e0 + CHUNK; if (e1 > E) e1 = E;
    for (int e = e0 + t; e < e1; e += 256) {
        int d = dst[e], s = src[e];
        int pos = atomicAdd(&cur[d >> BSHIFT], 1);
        packed[pos] = make_uint2((unsigned)s, (unsigned)d);
    }
}

__global__ __launch_bounds__(256) void k_fine(const uint2* __restrict__ packed,
                                              const int* __restrict__ bucketbase,
                                              int* __restrict__ offsets,
                                              int* __restrict__ csr_src,
                                              int N, int NBUK) {
    __shared__ int fcnt[256];
    __shared__ int wsum[4];
    int bucket = blockIdx.x, t = threadIdx.x;
    int lo = bucket << BSHIFT;
    int nn = N - lo; if (nn > 256) nn = 256;
    int ebase = bucketbase[bucket];
    int ecnt = bucketbase[bucket + 1] - ebase;
    fcnt[t] = 0;
    __syncthreads();
    for (int i = t; i < ecnt; i += 256) {
        uint2 p = packed[ebase + i];
        atomicAdd(&fcnt[(int)p.y - lo], 1);
    }
    __syncthreads();
    int v = fcnt[t];
    int lane = t & 63, wv = t >> 6;
    int s = v;
#pragma unroll
    for (int o = 1; o < 64; o <<= 1) {
        int u = __shfl_up(s, o, 64);
        if (lane >= o) s += u;
    }
    if (lane == 63) wsum[wv] = s;
    __syncthreads();
    int base = 0;
#pragma unroll
    for (int w = 0; w < 4; ++w) base += (w < wv) ? wsum[w] : 0;
    int excl = s + base - v;
    if (t < nn) offsets[lo + t] = ebase + excl;
    if (bucket == NBUK - 1 && t == 0) offsets[N] = ebase + ecnt;  // == E
    __syncthreads();
    fcnt[t] = excl;   // reuse as cursor
    __syncthreads();
    for (int i = t; i < ecnt; i += 256) {
        uint2 p = packed[ebase + i];
        int pos = atomicAdd(&fcnt[(int)p.y - lo], 1);
        csr_src[ebase + pos] = (int)p.x;
    }
}

// ---------------- W2 pre-split: hi/lo bf16, padded 40 -> 48 cols ----------------
__global__ __launch_bounds__(256) void k_splitW2(const float* __restrict__ W2,
                                                 short* __restrict__ w2h,
                                                 short* __restrict__ w2l) {
    int i = blockIdx.x * 256 + threadIdx.x;
    if (i < 64 * 48) {
        int row = i / 48, col = i % 48;
        short hi = 0, lo = 0;
        if (col < 40) splitbf(W2[row * 40 + col], hi, lo);
        w2h[i] = hi; w2l[i] = lo;
    }
}

// ---------------- Layer 1 GEMM via MFMA bf16 (plain; inputs are replay-constant) ----------------
// h1[N,64] = x[N,128] @ W1[128,64]. One wave = 16 rows; B in registers.
__global__ __launch_bounds__(256) void k_gemm1(const float* __restrict__ x,
                                               const float* __restrict__ W1,
                                               const float* __restrict__ att_s,
                                               const float* __restrict__ att_d,
                                               float* __restrict__ h1,
                                               float* __restrict__ a_s1,
                                               float* __restrict__ a_d1, int N) {
    int tid = threadIdx.x, wave = tid >> 6, lane = tid & 63;
    int n16 = lane & 15, q = lane >> 4;
    int nb = blockIdx.x * 64 + wave * 16;
    if (nb >= N) return;

    short8 bfr[4][4];
#pragma unroll
    for (int ct = 0; ct < 4; ++ct) {
        int n = ct * 16 + n16;
#pragma unroll
        for (int kc = 0; kc < 4; ++kc) {
            int k0 = kc * 32 + q * 8;
            short8 b;
#pragma unroll
            for (int j = 0; j < 8; ++j) b[j] = f2bf(W1[(k0 + j) * 64 + n]);
            bfr[ct][kc] = b;
        }
    }

    int arow = nb + n16; if (arow >= N) arow = N - 1;
    const float* xr = x + (size_t)arow * 128 + q * 8;
    short8 afr[4];
#pragma unroll
    for (int kc = 0; kc < 4; ++kc) {
        float4 u0 = *(const float4*)(xr + kc * 32);
        float4 u1 = *(const float4*)(xr + kc * 32 + 4);
        short8 a;
        a[0] = f2bf(u0.x); a[1] = f2bf(u0.y); a[2] = f2bf(u0.z); a[3] = f2bf(u0.w);
        a[4] = f2bf(u1.x); a[5] = f2bf(u1.y); a[6] = f2bf(u1.z); a[7] = f2bf(u1.w);
        afr[kc] = a;
    }

    floatx4 acc[4];
#pragma unroll
    for (int ct = 0; ct < 4; ++ct) {
        floatx4 c = {0.f, 0.f, 0.f, 0.f};
#pragma unroll
        for (int kc = 0; kc < 4; ++kc)
            c = __builtin_amdgcn_mfma_f32_16x16x32_bf16(afr[kc], bfr[ct][kc], c, 0, 0, 0);
        acc[ct] = c;
    }

#pragma unroll
    for (int ct = 0; ct < 4; ++ct) {
#pragma unroll
        for (int r = 0; r < 4; ++r) {
            int row = nb + q * 4 + r;
            if (row < N) h1[(size_t)row * 64 + ct * 16 + n16] = acc[ct][r];
        }
    }

#pragma unroll
    for (int ct = 0; ct < 4; ++ct) {
        float as = att_s[ct * 16 + n16];
        float ad = att_d[ct * 16 + n16];
#pragma unroll
        for (int r = 0; r < 4; ++r) {
            float ps = acc[ct][r] * as;
            float pd = acc[ct][r] * ad;
#pragma unroll
            for (int m = 1; m < 8; m <<= 1) {
                ps += __shfl_xor(ps, m, 64);
                pd += __shfl_xor(pd, m, 64);
            }
            int row = nb + q * 4 + r;
            if ((n16 & 7) == 0 && row < N) {
                int h = 2 * ct + (n16 >> 3);
                a_s1[row * 8 + h] = ps;
                a_d1[row * 8 + h] = pd;
            }
        }
    }
}

// ---------------- Layer 1 aggregation ----------------
__global__ __launch_bounds__(256) void k_agg1(const float* __restrict__ h1,
                                              const float* __restrict__ a_s1,
                                              const float* __restrict__ a_d1,
                                              const int* __restrict__ offsets,
                                              const int* __restrict__ csr_src,
                                              const float* __restrict__ b1,
                                              float* __restrict__ y1, int N) {
    int wave = threadIdx.x >> 6, lane = threadIdx.x & 63;
    int d = blockIdx.x * 4 + wave;
    if (d >= N) return;
    int h = lane >> 3;
    float ad = a_d1[d * 8 + h];
    float w0 = lrelu_exp(a_s1[d * 8 + h] + ad);
    float acc = w0 * h1[(size_t)d * 64 + lane];
    float wsum = w0;
    int i0 = offsets[d], i1 = offsets[d + 1];
    for (int base = i0; base < i1; base += 64) {
        int m = i1 - base; if (m > 64) m = 64;
        int sv = (lane < m) ? csr_src[base + lane] : 0;
        int j = 0;
        for (; j + 4 <= m; j += 4) {
            int s0 = __shfl(sv, j, 64), s1 = __shfl(sv, j + 1, 64),
                s2 = __shfl(sv, j + 2, 64), s3 = __shfl(sv, j + 3, 64);
            float a0 = a_s1[s0 * 8 + h], a1 = a_s1[s1 * 8 + h],
                  a2 = a_s1[s2 * 8 + h], a3 = a_s1[s3 * 8 + h];
            float v0 = h1[(size_t)s0 * 64 + lane], v1 = h1[(size_t)s1 * 64 + lane],
                  v2 = h1[(size_t)s2 * 64 + lane], v3 = h1[(size_t)s3 * 64 + lane];
            float w;
            w = lrelu_exp(a0 + ad); acc = fmaf(w, v0, acc); wsum += w;
            w = lrelu_exp(a1 + ad); acc = fmaf(w, v1, acc); wsum += w;
            w = lrelu_exp(a2 + ad); acc = fmaf(w, v2, acc); wsum += w;
            w = lrelu_exp(a3 + ad); acc = fmaf(w, v3, acc); wsum += w;
        }
        for (; j < m; ++j) {
            int s = __shfl(sv, j, 64);
            float w = lrelu_exp(a_s1[s * 8 + h] + ad);
            acc = fmaf(w, h1[(size_t)s * 64 + lane], acc);
            wsum += w;
        }
    }
    float o = acc / (wsum + 1e-16f) + b1[lane];
    y1[(size_t)d * 64 + lane] = o > 0.f ? o : expm1f(o);  // ELU
}

// ---------------- Layer 2 GEMM, split-bf16 (y1 is replay-variant -> needs fp32-class) ----------
// h2[N,40] = y1[N,64] @ W2[64,40]; W2 pre-split into w2h/w2l (48-col padded).
__global__ __launch_bounds__(256) void k_gemm2(const float* __restrict__ y1,
                                               const short* __restrict__ w2h,
                                               const short* __restrict__ w2l,
                                               const float* __restrict__ att_s,
                                               const float* __restrict__ att_d,
                                               float* __restrict__ h2,
                                               float* __restrict__ a2s,
                                               float* __restrict__ a2d, int N) {
    int tid = threadIdx.x, wave = tid >> 6, lane = tid & 63;
    int n16 = lane & 15, q = lane >> 4;
    int nb = blockIdx.x * 64 + wave * 16;
    if (nb >= N) return;

    int arow = nb + n16; if (arow >= N) arow = N - 1;
    const float* yr = y1 + (size_t)arow * 64 + q * 8;
    short8 ah[2], al[2];
#pragma unroll
    for (int kc = 0; kc < 2; ++kc) {
        float4 u0 = *(const float4*)(yr + kc * 32);
        float4 u1 = *(const float4*)(yr + kc * 32 + 4);
        short8 h, l; short hi, lo;
        splitbf(u0.x, hi, lo); h[0] = hi; l[0] = lo;
        splitbf(u0.y, hi, lo); h[1] = hi; l[1] = lo;
        splitbf(u0.z, hi, lo); h[2] = hi; l[2] = lo;
        splitbf(u0.w, hi, lo); h[3] = hi; l[3] = lo;
        splitbf(u1.x, hi, lo); h[4] = hi; l[4] = lo;
        splitbf(u1.y, hi, lo); h[5] = hi; l[5] = lo;
        splitbf(u1.z, hi, lo); h[6] = hi; l[6] = lo;
        splitbf(u1.w, hi, lo); h[7] = hi; l[7] = lo;
        ah[kc] = h; al[kc] = l;
    }

    float psr[4] = {0.f, 0.f, 0.f, 0.f}, pdr[4] = {0.f, 0.f, 0.f, 0.f};
#pragma unroll
    for (int ct = 0; ct < 3; ++ct) {
        int n = ct * 16 + n16;
        short8 bh0, bh1, bl0, bl1;
#pragma unroll
        for (int j = 0; j < 8; ++j) {
            int k0 = q * 8 + j;
            bh0[j] = w2h[k0 * 48 + n];
            bl0[j] = w2l[k0 * 48 + n];
            bh1[j] = w2h[(32 + k0) * 48 + n];
            bl1[j] = w2l[(32 + k0) * 48 + n];
        }
        floatx4 c = {0.f, 0.f, 0.f, 0.f};
        c = __builtin_amdgcn_mfma_f32_16x16x32_bf16(ah[0], bl0, c, 0, 0, 0);
        c = __builtin_amdgcn_mfma_f32_16x16x32_bf16(al[0], bh0, c, 0, 0, 0);
        c = __builtin_amdgcn_mfma_f32_16x16x32_bf16(ah[0], bh0, c, 0, 0, 0);
        c = __builtin_amdgcn_mfma_f32_16x16x32_bf16(ah[1], bl1, c, 0, 0, 0);
        c = __builtin_amdgcn_mfma_f32_16x16x32_bf16(al[1], bh1, c, 0, 0, 0);
        c = __builtin_amdgcn_mfma_f32_16x16x32_bf16(ah[1], bh1, c, 0, 0, 0);

        int col = ct * 16 + n16;
#pragma unroll
        for (int r = 0; r < 4; ++r) {
            int row = nb + q * 4 + r;
            if (col < 40 && row < N) h2[(size_t)row * 40 + col] = c[r];
        }
        float asv = (col < 40) ? att_s[col] : 0.f;
        float adv = (col < 40) ? att_d[col] : 0.f;
#pragma unroll
        for (int r = 0; r < 4; ++r) {
            psr[r] = fmaf(c[r], asv, psr[r]);
            pdr[r] = fmaf(c[r], adv, pdr[r]);
        }
    }
#pragma unroll
    for (int r = 0; r < 4; ++r) {
        float ps = psr[r], pd = pdr[r];
#pragma unroll
        for (int m = 1; m < 16; m <<= 1) {
            ps += __shfl_xor(ps, m, 64);
            pd += __shfl_xor(pd, m, 64);
        }
        int row = nb + q * 4 + r;
        if (n16 == 0 && row < N) { a2s[row] = ps; a2d[row] = pd; }
    }
}

// ---------------- Layer 2 aggregation + log_softmax ----------------
__global__ __launch_bounds__(256) void k_agg2(const float* __restrict__ h2,
                                              const float* __restrict__ a2s,
                                              const float* __restrict__ a2d,
                                              const int* __restrict__ offsets,
                                              const int* __restrict__ csr_src,
                                              const float* __restrict__ b2,
                                              float* __restrict__ out, int N) {
    int wave = threadIdx.x >> 6, lane = threadIdx.x & 63;
    int d = blockIdx.x * 4 + wave;
    if (d >= N) return;
    float ad = a2d[d];
    float w0 = lrelu_exp(a2s[d] + ad);
    float acc = (lane < 40) ? w0 * h2[(size_t)d * 40 + lane] : 0.f;
    float wsum_l = 0.f;
    int i0 = offsets[d], i1 = offsets[d + 1];
    for (int base = i0; base < i1; base += 64) {
        int m = i1 - base; if (m > 64) m = 64;
        int sv = 0; float wv = 0.f;
        if (lane < m) {
            sv = csr_src[base + lane];
            wv = lrelu_exp(a2s[sv] + ad);
        }
        wsum_l += wv;
        int j = 0;
        for (; j + 4 <= m; j += 4) {
            int s0 = __shfl(sv, j, 64), s1 = __shfl(sv, j + 1, 64),
                s2 = __shfl(sv, j + 2, 64), s3 = __shfl(sv, j + 3, 64);
            float wq0 = __shfl(wv, j, 64), wq1 = __shfl(wv, j + 1, 64),
                  wq2 = __shfl(wv, j + 2, 64), wq3 = __shfl(wv, j + 3, 64);
            if (lane < 40) {
                float v0 = h2[(size_t)s0 * 40 + lane], v1 = h2[(size_t)s1 * 40 + lane],
                      v2 = h2[(size_t)s2 * 40 + lane], v3 = h2[(size_t)s3 * 40 + lane];
                acc = fmaf(wq0, v0, acc); acc = fmaf(wq1, v1, acc);
                acc = fmaf(wq2, v2, acc); acc = fmaf(wq3, v3, acc);
            }
        }
        for (; j < m; ++j) {
            int s = __shfl(sv, j, 64);
            float wq = __shfl(wv, j, 64);
            if (lane < 40) acc = fmaf(wq, h2[(size_t)s * 40 + lane], acc);
        }
    }
#pragma unroll
    for (int mm = 1; mm < 64; mm <<= 1) wsum_l += __shfl_xor(wsum_l, mm, 64);
    float wsum = wsum_l + w0;
    float o = (lane < 40) ? (acc / (wsum + 1e-16f) + b2[lane]) : -INFINITY;
    float mx = o;
#pragma unroll
    for (int mm = 1; mm < 64; mm <<= 1) mx = fmaxf(mx, __shfl_xor(mx, mm, 64));
    float ex = (lane < 40) ? __expf(o - mx) : 0.f;
#pragma unroll
    for (int mm = 1; mm < 64; mm <<= 1) ex += __shfl_xor(ex, mm, 64);
    if (lane < 40) out[(size_t)d * 40 + lane] = o - mx - __logf(ex);
}

// ---------------- launcher ----------------

extern "C" void kernel_launch(void* const* d_in, const int* in_sizes, int n_in,
                              void* d_out, int out_size, void* d_ws, size_t ws_size,
                              hipStream_t stream) {
    const float* x   = (const float*)d_in[0];
    const int*   ei  = (const int*)d_in[1];
    const float* W1  = (const float*)d_in[2];
    const float* as1 = (const float*)d_in[3];
    const float* ad1 = (const float*)d_in[4];
    const float* b1  = (const float*)d_in[5];
    const float* W2  = (const float*)d_in[6];
    const float* as2 = (const float*)d_in[7];
    const float* ad2 = (const float*)d_in[8];
    const float* b2  = (const float*)d_in[9];
    float* out = (float*)d_out;

    int N = in_sizes[0] / 128;   // 100000
    int E = in_sizes[1] / 2;     // 1600000
    const int* src = ei;
    const int* dst = ei + E;

    int NBUK = (N + 255) >> BSHIFT;          // 391
    int CHUNK = 8192;
    while ((E + CHUNK - 1) / CHUNK > 256) CHUNK <<= 1;
    int NBLK = (E + CHUNK - 1) / CHUNK;      // 196

    char* ws = (char*)d_ws;
    size_t off = 0;
    auto alloc = [&](size_t bytes) -> char* {
        char* p = ws + off;
        off += (bytes + 255) & ~(size_t)255;
        return p;
    };
    float* h1      = (float*)alloc((size_t)N * 64 * 4);
    float* a_s1    = (float*)alloc((size_t)N * 8 * 4);
    float* a_d1    = (float*)alloc((size_t)N * 8 * 4);
    float* y1      = (float*)alloc((size_t)N * 64 * 4);
    // h2 (16 MB) and packed (12.8 MB) are temporally disjoint: share region.
    size_t shared_sz = (size_t)N * 40 * 4;
    if ((size_t)E * 8 > shared_sz) shared_sz = (size_t)E * 8;
    char*  region  = alloc(shared_sz);
    float* h2      = (float*)region;
    uint2* packed  = (uint2*)region;
    float* a2s     = (float*)alloc((size_t)N * 4);
    float* a2d     = (float*)alloc((size_t)N * 4);
    int*   offsets = (int*)alloc((size_t)(N + 1) * 4);
    int*   csr_src = (int*)alloc((size_t)E * 4);
    int*   blockhist  = (int*)alloc((size_t)NBUK * NBLK * 4);
    int*   bucketbase = (int*)alloc((size_t)(NBUK + 1) * 4);
    short* w2h     = (short*)alloc((size_t)64 * 48 * 2);
    short* w2l     = (short*)alloc((size_t)64 * 48 * 2);

    int nb = (N + 3) / 4;
    int gb = (N + 63) / 64;

    k_hist<<<NBLK, 256, 0, stream>>>(dst, E, CHUNK, NBLK, NBUK, blockhist);
    k_bucket_scan<<<1, 512, 0, stream>>>(blockhist, bucketbase, NBLK, NBUK);
    k_colscan<<<NBUK, 256, 0, stream>>>(blockhist, bucketbase, NBLK);
    k_partition<<<NBLK, 256, 0, stream>>>(src, dst, E, CHUNK, NBLK, NBUK, blockhist, packed);
    k_fine<<<NBUK, 256, 0, stream>>>(packed, bucketbase, offsets, csr_src, N, NBUK);
    k_splitW2<<<12, 256, 0, stream>>>(W2, w2h, w2l);
    k_gemm1<<<gb, 256, 0, stream>>>(x, W1, as1, ad1, h1, a_s1, a_d1, N);
    k_agg1<<<nb, 256, 0, stream>>>(h1, a_s1, a_d1, offsets, csr_src, b1, y1, N);
    k_gemm2<<<gb, 256, 0, stream>>>(y1, w2h, w2l, as2, ad2, h2, a2s, a2d, N);
    k_agg2<<<nb, 256, 0, stream>>>(h2, a2s, a2d, offsets, csr_src, b2, out, N);
}

// Round 8
// 352.878 us; speedup vs baseline: 2.9997x; 1.0618x over previous
//
#include <hip/hip_runtime.h>
#include <math.h>

#define NEG_SLOPE 0.2f
#define BSHIFT 8            // 256 nodes per bucket
#define MAXBUK 512          // supports N up to 131072

typedef __attribute__((ext_vector_type(8))) short short8;   // 8 bf16 (MFMA A/B frag)
typedef __attribute__((ext_vector_type(4))) float floatx4;  // MFMA C/D frag

static __device__ __forceinline__ float lrelu_exp(float e) {
    e = e > 0.f ? e : NEG_SLOPE * e;
    return __expf(e);
}

// fp32 -> bf16 (round-to-nearest-even)
static __device__ __forceinline__ short f2bf(float f) {
    union { float f; unsigned u; } v; v.f = f;
    unsigned r = v.u + 0x7FFFu + ((v.u >> 16) & 1u);
    return (short)(r >> 16);
}
// bf16 bits -> fp32 (exact)
static __device__ __forceinline__ float bf2f(unsigned short s) {
    union { float f; unsigned u; } v;
    v.u = ((unsigned)s) << 16;
    return v.f;
}
// split f into hi+lo bf16 pair (covers ~16 mantissa bits)
static __device__ __forceinline__ void splitbf(float f, short& hi, short& lo) {
    hi = f2bf(f);
    lo = f2bf(f - bf2f((unsigned short)hi));
}

// ================= CSR build: LDS-bucketed partition (no global data atomics) =================

__global__ __launch_bounds__(256) void k_hist(const int* __restrict__ dst, int E, int CHUNK,
                                              int NBLK, int NBUK, int* __restrict__ blockhist) {
    __shared__ int hist[MAXBUK];
    int t = threadIdx.x, b = blockIdx.x;
    for (int i = t; i < NBUK; i += 256) hist[i] = 0;
    __syncthreads();
    int e0 = b * CHUNK, e1 = e0 + CHUNK; if (e1 > E) e1 = E;
    for (int e = e0 + t; e < e1; e += 256) atomicAdd(&hist[dst[e] >> BSHIFT], 1);
    __syncthreads();
    for (int i = t; i < NBUK; i += 256) blockhist[i * NBLK + b] = hist[i];
}

__global__ __launch_bounds__(512) void k_bucket_scan(const int* __restrict__ blockhist,
                                                     int* __restrict__ bucketbase,
                                                     int NBLK, int NBUK) {
    __shared__ int sh[512];
    int t = threadIdx.x;
    int tot = 0;
    if (t < NBUK) {
        const int* p = blockhist + (size_t)t * NBLK;
        for (int k = 0; k < NBLK; ++k) tot += p[k];
    }
    sh[t] = tot;
    __syncthreads();
#pragma unroll
    for (int o = 1; o < 512; o <<= 1) {
        int u = (t >= o) ? sh[t - o] : 0;
        __syncthreads();
        sh[t] += u;
        __syncthreads();
    }
    if (t < NBUK) bucketbase[t] = sh[t] - tot;
    if (t == NBUK - 1) bucketbase[NBUK] = sh[t];
}

__global__ __launch_bounds__(256) void k_colscan(int* __restrict__ blockhist,
                                                 const int* __restrict__ bucketbase,
                                                 int NBLK) {
    int bucket = blockIdx.x, t = threadIdx.x;
    int v = (t < NBLK) ? blockhist[(size_t)bucket * NBLK + t] : 0;
    int lane = t & 63, wv = t >> 6;
    int s = v;
#pragma unroll
    for (int o = 1; o < 64; o <<= 1) {
        int u = __shfl_up(s, o, 64);
        if (lane >= o) s += u;
    }
    __shared__ int wsum[4];
    if (lane == 63) wsum[wv] = s;
    __syncthreads();
    int base = 0;
#pragma unroll
    for (int w = 0; w < 4; ++w) base += (w < wv) ? wsum[w] : 0;
    int excl = s + base - v + bucketbase[bucket];
    if (t < NBLK) blockhist[(size_t)bucket * NBLK + t] = excl;
}

// packed record: (src << 8) | (dst & 255)   [src < 2^24; bucket id recovers dst high bits]
__global__ __launch_bounds__(256) void k_partition(const int* __restrict__ src,
                                                   const int* __restrict__ dst, int E, int CHUNK,
                                                   int NBLK, int NBUK,
                                                   const int* __restrict__ blockhist,
                                                   unsigned* __restrict__ packed) {
    __shared__ int cur[MAXBUK];
    int t = threadIdx.x, b = blockIdx.x;
    for (int i = t; i < NBUK; i += 256) cur[i] = blockhist[(size_t)i * NBLK + b];
    __syncthreads();
    int e0 = b * CHUNK, e1 = e0 + CHUNK; if (e1 > E) e1 = E;
    for (int e = e0 + t; e < e1; e += 256) {
        int d = dst[e], s = src[e];
        int pos = atomicAdd(&cur[d >> BSHIFT], 1);
        packed[pos] = ((unsigned)s << 8) | ((unsigned)d & 255u);
    }
}

__global__ __launch_bounds__(256) void k_fine(const unsigned* __restrict__ packed,
                                              const int* __restrict__ bucketbase,
                                              int* __restrict__ offsets,
                                              int* __restrict__ csr_src,
                                              int N, int NBUK) {
    __shared__ int fcnt[256];
    __shared__ int wsum[4];
    int bucket = blockIdx.x, t = threadIdx.x;
    int lo = bucket << BSHIFT;
    int nn = N - lo; if (nn > 256) nn = 256;
    int ebase = bucketbase[bucket];
    int ecnt = bucketbase[bucket + 1] - ebase;
    fcnt[t] = 0;
    __syncthreads();
    for (int i = t; i < ecnt; i += 256) {
        unsigned p = packed[ebase + i];
        atomicAdd(&fcnt[p & 255u], 1);
    }
    __syncthreads();
    int v = fcnt[t];
    int lane = t & 63, wv = t >> 6;
    int s = v;
#pragma unroll
    for (int o = 1; o < 64; o <<= 1) {
        int u = __shfl_up(s, o, 64);
        if (lane >= o) s += u;
    }
    if (lane == 63) wsum[wv] = s;
    __syncthreads();
    int base = 0;
#pragma unroll
    for (int w = 0; w < 4; ++w) base += (w < wv) ? wsum[w] : 0;
    int excl = s + base - v;
    if (t < nn) offsets[lo + t] = ebase + excl;
    if (bucket == NBUK - 1 && t == 0) offsets[N] = ebase + ecnt;  // == E
    __syncthreads();
    fcnt[t] = excl;   // reuse as cursor
    __syncthreads();
    for (int i = t; i < ecnt; i += 256) {
        unsigned p = packed[ebase + i];
        int pos = atomicAdd(&fcnt[p & 255u], 1);
        csr_src[ebase + pos] = (int)(p >> 8);
    }
}

// ---------------- W2 pre-split: hi/lo bf16, padded 40 -> 48 cols ----------------
__global__ __launch_bounds__(256) void k_splitW2(const float* __restrict__ W2,
                                                 short* __restrict__ w2h,
                                                 short* __restrict__ w2l) {
    int i = blockIdx.x * 256 + threadIdx.x;
    if (i < 64 * 48) {
        int row = i / 48, col = i % 48;
        short hi = 0, lo = 0;
        if (col < 40) splitbf(W2[row * 40 + col], hi, lo);
        w2h[i] = hi; w2l[i] = lo;
    }
}

// ---------------- Layer 1 GEMM via MFMA bf16 (plain; inputs replay-constant) ----------------
// h1b[N,64] (bf16) = x[N,128] @ W1[128,64]. One wave = 16 rows; B in registers.
__global__ __launch_bounds__(256) void k_gemm1(const float* __restrict__ x,
                                               const float* __restrict__ W1,
                                               const float* __restrict__ att_s,
                                               const float* __restrict__ att_d,
                                               unsigned short* __restrict__ h1b,
                                               float* __restrict__ a_s1,
                                               float* __restrict__ a_d1, int N) {
    int tid = threadIdx.x, wave = tid >> 6, lane = tid & 63;
    int n16 = lane & 15, q = lane >> 4;
    int nb = blockIdx.x * 64 + wave * 16;
    if (nb >= N) return;

    short8 bfr[4][4];
#pragma unroll
    for (int ct = 0; ct < 4; ++ct) {
        int n = ct * 16 + n16;
#pragma unroll
        for (int kc = 0; kc < 4; ++kc) {
            int k0 = kc * 32 + q * 8;
            short8 b;
#pragma unroll
            for (int j = 0; j < 8; ++j) b[j] = f2bf(W1[(k0 + j) * 64 + n]);
            bfr[ct][kc] = b;
        }
    }

    int arow = nb + n16; if (arow >= N) arow = N - 1;
    const float* xr = x + (size_t)arow * 128 + q * 8;
    short8 afr[4];
#pragma unroll
    for (int kc = 0; kc < 4; ++kc) {
        float4 u0 = *(const float4*)(xr + kc * 32);
        float4 u1 = *(const float4*)(xr + kc * 32 + 4);
        short8 a;
        a[0] = f2bf(u0.x); a[1] = f2bf(u0.y); a[2] = f2bf(u0.z); a[3] = f2bf(u0.w);
        a[4] = f2bf(u1.x); a[5] = f2bf(u1.y); a[6] = f2bf(u1.z); a[7] = f2bf(u1.w);
        afr[kc] = a;
    }

    floatx4 acc[4];
#pragma unroll
    for (int ct = 0; ct < 4; ++ct) {
        floatx4 c = {0.f, 0.f, 0.f, 0.f};
#pragma unroll
        for (int kc = 0; kc < 4; ++kc)
            c = __builtin_amdgcn_mfma_f32_16x16x32_bf16(afr[kc], bfr[ct][kc], c, 0, 0, 0);
        acc[ct] = c;
    }

#pragma unroll
    for (int ct = 0; ct < 4; ++ct) {
#pragma unroll
        for (int r = 0; r < 4; ++r) {
            int row = nb + q * 4 + r;
            if (row < N) h1b[(size_t)row * 64 + ct * 16 + n16] = (unsigned short)f2bf(acc[ct][r]);
        }
    }

#pragma unroll
    for (int ct = 0; ct < 4; ++ct) {
        float as = att_s[ct * 16 + n16];
        float ad = att_d[ct * 16 + n16];
#pragma unroll
        for (int r = 0; r < 4; ++r) {
            float ps = acc[ct][r] * as;
            float pd = acc[ct][r] * ad;
#pragma unroll
            for (int m = 1; m < 8; m <<= 1) {
                ps += __shfl_xor(ps, m, 64);
                pd += __shfl_xor(pd, m, 64);
            }
            int row = nb + q * 4 + r;
            if ((n16 & 7) == 0 && row < N) {
                int h = 2 * ct + (n16 >> 3);
                a_s1[row * 8 + h] = ps;
                a_d1[row * 8 + h] = pd;
            }
        }
    }
}

// ---------------- Layer 1 aggregation (bf16 h1 gathers) ----------------
__global__ __launch_bounds__(256) void k_agg1(const unsigned short* __restrict__ h1b,
                                              const float* __restrict__ a_s1,
                                              const float* __restrict__ a_d1,
                                              const int* __restrict__ offsets,
                                              const int* __restrict__ csr_src,
                                              const float* __restrict__ b1,
                                              float* __restrict__ y1, int N) {
    int wave = threadIdx.x >> 6, lane = threadIdx.x & 63;
    int d = blockIdx.x * 4 + wave;
    if (d >= N) return;
    int h = lane >> 3;
    float ad = a_d1[d * 8 + h];
    float w0 = lrelu_exp(a_s1[d * 8 + h] + ad);
    float acc = w0 * bf2f(h1b[(size_t)d * 64 + lane]);
    float wsum = w0;
    int i0 = offsets[d], i1 = offsets[d + 1];
    for (int base = i0; base < i1; base += 64) {
        int m = i1 - base; if (m > 64) m = 64;
        int sv = (lane < m) ? csr_src[base + lane] : 0;
        int j = 0;
        for (; j + 4 <= m; j += 4) {
            int s0 = __shfl(sv, j, 64), s1 = __shfl(sv, j + 1, 64),
                s2 = __shfl(sv, j + 2, 64), s3 = __shfl(sv, j + 3, 64);
            float a0 = a_s1[s0 * 8 + h], a1 = a_s1[s1 * 8 + h],
                  a2 = a_s1[s2 * 8 + h], a3 = a_s1[s3 * 8 + h];
            float v0 = bf2f(h1b[(size_t)s0 * 64 + lane]), v1 = bf2f(h1b[(size_t)s1 * 64 + lane]),
                  v2 = bf2f(h1b[(size_t)s2 * 64 + lane]), v3 = bf2f(h1b[(size_t)s3 * 64 + lane]);
            float w;
            w = lrelu_exp(a0 + ad); acc = fmaf(w, v0, acc); wsum += w;
            w = lrelu_exp(a1 + ad); acc = fmaf(w, v1, acc); wsum += w;
            w = lrelu_exp(a2 + ad); acc = fmaf(w, v2, acc); wsum += w;
            w = lrelu_exp(a3 + ad); acc = fmaf(w, v3, acc); wsum += w;
        }
        for (; j < m; ++j) {
            int s = __shfl(sv, j, 64);
            float w = lrelu_exp(a_s1[s * 8 + h] + ad);
            acc = fmaf(w, bf2f(h1b[(size_t)s * 64 + lane]), acc);
            wsum += w;
        }
    }
    float o = acc / (wsum + 1e-16f) + b1[lane];
    y1[(size_t)d * 64 + lane] = o > 0.f ? o : expm1f(o);  // ELU (y1 stays fp32!)
}

// ---------------- Layer 2 GEMM, split-bf16 (y1 replay-variant -> fp32-class needed) ----------
// h2b[N,40] (bf16) = y1[N,64] @ W2[64,40]; W2 pre-split into w2h/w2l (48-col padded).
__global__ __launch_bounds__(256) void k_gemm2(const float* __restrict__ y1,
                                               const short* __restrict__ w2h,
                                               const short* __restrict__ w2l,
                                               const float* __restrict__ att_s,
                                               const float* __restrict__ att_d,
                                               unsigned short* __restrict__ h2b,
                                               float* __restrict__ a2s,
                                               float* __restrict__ a2d, int N) {
    int tid = threadIdx.x, wave = tid >> 6, lane = tid & 63;
    int n16 = lane & 15, q = lane >> 4;
    int nb = blockIdx.x * 64 + wave * 16;
    if (nb >= N) return;

    int arow = nb + n16; if (arow >= N) arow = N - 1;
    const float* yr = y1 + (size_t)arow * 64 + q * 8;
    short8 ah[2], al[2];
#pragma unroll
    for (int kc = 0; kc < 2; ++kc) {
        float4 u0 = *(const float4*)(yr + kc * 32);
        float4 u1 = *(const float4*)(yr + kc * 32 + 4);
        short8 h, l; short hi, lo;
        splitbf(u0.x, hi, lo); h[0] = hi; l[0] = lo;
        splitbf(u0.y, hi, lo); h[1] = hi; l[1] = lo;
        splitbf(u0.z, hi, lo); h[2] = hi; l[2] = lo;
        splitbf(u0.w, hi, lo); h[3] = hi; l[3] = lo;
        splitbf(u1.x, hi, lo); h[4] = hi; l[4] = lo;
        splitbf(u1.y, hi, lo); h[5] = hi; l[5] = lo;
        splitbf(u1.z, hi, lo); h[6] = hi; l[6] = lo;
        splitbf(u1.w, hi, lo); h[7] = hi; l[7] = lo;
        ah[kc] = h; al[kc] = l;
    }

    float psr[4] = {0.f, 0.f, 0.f, 0.f}, pdr[4] = {0.f, 0.f, 0.f, 0.f};
#pragma unroll
    for (int ct = 0; ct < 3; ++ct) {
        int n = ct * 16 + n16;
        short8 bh0, bh1, bl0, bl1;
#pragma unroll
        for (int j = 0; j < 8; ++j) {
            int k0 = q * 8 + j;
            bh0[j] = w2h[k0 * 48 + n];
            bl0[j] = w2l[k0 * 48 + n];
            bh1[j] = w2h[(32 + k0) * 48 + n];
            bl1[j] = w2l[(32 + k0) * 48 + n];
        }
        floatx4 c = {0.f, 0.f, 0.f, 0.f};
        c = __builtin_amdgcn_mfma_f32_16x16x32_bf16(ah[0], bl0, c, 0, 0, 0);
        c = __builtin_amdgcn_mfma_f32_16x16x32_bf16(al[0], bh0, c, 0, 0, 0);
        c = __builtin_amdgcn_mfma_f32_16x16x32_bf16(ah[0], bh0, c, 0, 0, 0);
        c = __builtin_amdgcn_mfma_f32_16x16x32_bf16(ah[1], bl1, c, 0, 0, 0);
        c = __builtin_amdgcn_mfma_f32_16x16x32_bf16(al[1], bh1, c, 0, 0, 0);
        c = __builtin_amdgcn_mfma_f32_16x16x32_bf16(ah[1], bh1, c, 0, 0, 0);

        int col = ct * 16 + n16;
#pragma unroll
        for (int r = 0; r < 4; ++r) {
            int row = nb + q * 4 + r;
            if (col < 40 && row < N) h2b[(size_t)row * 40 + col] = (unsigned short)f2bf(c[r]);
        }
        float asv = (col < 40) ? att_s[col] : 0.f;
        float adv = (col < 40) ? att_d[col] : 0.f;
#pragma unroll
        for (int r = 0; r < 4; ++r) {
            psr[r] = fmaf(c[r], asv, psr[r]);
            pdr[r] = fmaf(c[r], adv, pdr[r]);
        }
    }
#pragma unroll
    for (int r = 0; r < 4; ++r) {
        float ps = psr[r], pd = pdr[r];
#pragma unroll
        for (int m = 1; m < 16; m <<= 1) {
            ps += __shfl_xor(ps, m, 64);
            pd += __shfl_xor(pd, m, 64);
        }
        int row = nb + q * 4 + r;
        if (n16 == 0 && row < N) { a2s[row] = ps; a2d[row] = pd; }
    }
}

// ---------------- Layer 2 aggregation (bf16 h2 gathers) + log_softmax ----------------
__global__ __launch_bounds__(256) void k_agg2(const unsigned short* __restrict__ h2b,
                                              const float* __restrict__ a2s,
                                              const float* __restrict__ a2d,
                                              const int* __restrict__ offsets,
                                              const int* __restrict__ csr_src,
                                              const float* __restrict__ b2,
                                              float* __restrict__ out, int N) {
    int wave = threadIdx.x >> 6, lane = threadIdx.x & 63;
    int d = blockIdx.x * 4 + wave;
    if (d >= N) return;
    float ad = a2d[d];
    float w0 = lrelu_exp(a2s[d] + ad);
    float acc = (lane < 40) ? w0 * bf2f(h2b[(size_t)d * 40 + lane]) : 0.f;
    float wsum_l = 0.f;
    int i0 = offsets[d], i1 = offsets[d + 1];
    for (int base = i0; base < i1; base += 64) {
        int m = i1 - base; if (m > 64) m = 64;
        int sv = 0; float wv = 0.f;
        if (lane < m) {
            sv = csr_src[base + lane];
            wv = lrelu_exp(a2s[sv] + ad);
        }
        wsum_l += wv;
        int j = 0;
        for (; j + 4 <= m; j += 4) {
            int s0 = __shfl(sv, j, 64), s1 = __shfl(sv, j + 1, 64),
                s2 = __shfl(sv, j + 2, 64), s3 = __shfl(sv, j + 3, 64);
            float wq0 = __shfl(wv, j, 64), wq1 = __shfl(wv, j + 1, 64),
                  wq2 = __shfl(wv, j + 2, 64), wq3 = __shfl(wv, j + 3, 64);
            if (lane < 40) {
                float v0 = bf2f(h2b[(size_t)s0 * 40 + lane]), v1 = bf2f(h2b[(size_t)s1 * 40 + lane]),
                      v2 = bf2f(h2b[(size_t)s2 * 40 + lane]), v3 = bf2f(h2b[(size_t)s3 * 40 + lane]);
                acc = fmaf(wq0, v0, acc); acc = fmaf(wq1, v1, acc);
                acc = fmaf(wq2, v2, acc); acc = fmaf(wq3, v3, acc);
            }
        }
        for (; j < m; ++j) {
            int s = __shfl(sv, j, 64);
            float wq = __shfl(wv, j, 64);
            if (lane < 40) acc = fmaf(wq, bf2f(h2b[(size_t)s * 40 + lane]), acc);
        }
    }
#pragma unroll
    for (int mm = 1; mm < 64; mm <<= 1) wsum_l += __shfl_xor(wsum_l, mm, 64);
    float wsum = wsum_l + w0;
    float o = (lane < 40) ? (acc / (wsum + 1e-16f) + b2[lane]) : -INFINITY;
    float mx = o;
#pragma unroll
    for (int mm = 1; mm < 64; mm <<= 1) mx = fmaxf(mx, __shfl_xor(mx, mm, 64));
    float ex = (lane < 40) ? __expf(o - mx) : 0.f;
#pragma unroll
    for (int mm = 1; mm < 64; mm <<= 1) ex += __shfl_xor(ex, mm, 64);
    if (lane < 40) out[(size_t)d * 40 + lane] = o - mx - __logf(ex);
}

// ---------------- launcher ----------------

extern "C" void kernel_launch(void* const* d_in, const int* in_sizes, int n_in,
                              void* d_out, int out_size, void* d_ws, size_t ws_size,
                              hipStream_t stream) {
    const float* x   = (const float*)d_in[0];
    const int*   ei  = (const int*)d_in[1];
    const float* W1  = (const float*)d_in[2];
    const float* as1 = (const float*)d_in[3];
    const float* ad1 = (const float*)d_in[4];
    const float* b1  = (const float*)d_in[5];
    const float* W2  = (const float*)d_in[6];
    const float* as2 = (const float*)d_in[7];
    const float* ad2 = (const float*)d_in[8];
    const float* b2  = (const float*)d_in[9];
    float* out = (float*)d_out;

    int N = in_sizes[0] / 128;   // 100000
    int E = in_sizes[1] / 2;     // 1600000
    const int* src = ei;
    const int* dst = ei + E;

    int NBUK = (N + 255) >> BSHIFT;          // 391
    int CHUNK = 8192;
    while ((E + CHUNK - 1) / CHUNK > 256) CHUNK <<= 1;
    int NBLK = (E + CHUNK - 1) / CHUNK;      // 196

    char* ws = (char*)d_ws;
    size_t off = 0;
    auto alloc = [&](size_t bytes) -> char* {
        char* p = ws + off;
        off += (bytes + 255) & ~(size_t)255;
        return p;
    };
    unsigned short* h1b = (unsigned short*)alloc((size_t)N * 64 * 2);   // bf16
    float* a_s1    = (float*)alloc((size_t)N * 8 * 4);
    float* a_d1    = (float*)alloc((size_t)N * 8 * 4);
    float* y1      = (float*)alloc((size_t)N * 64 * 4);                 // fp32 (precision-critical)
    // h2b (bf16, 8 MB) and packed (uint, 6.4 MB) are temporally disjoint: share region.
    size_t shared_sz = (size_t)N * 40 * 2;
    if ((size_t)E * 4 > shared_sz) shared_sz = (size_t)E * 4;
    char*  region  = alloc(shared_sz);
    unsigned short* h2b = (unsigned short*)region;
    unsigned* packed    = (unsigned*)region;
    float* a2s     = (float*)alloc((size_t)N * 4);
    float* a2d     = (float*)alloc((size_t)N * 4);
    int*   offsets = (int*)alloc((size_t)(N + 1) * 4);
    int*   csr_src = (int*)alloc((size_t)E * 4);
    int*   blockhist  = (int*)alloc((size_t)NBUK * NBLK * 4);
    int*   bucketbase = (int*)alloc((size_t)(NBUK + 1) * 4);
    short* w2h     = (short*)alloc((size_t)64 * 48 * 2);
    short* w2l     = (short*)alloc((size_t)64 * 48 * 2);

    int nb = (N + 3) / 4;
    int gb = (N + 63) / 64;

    k_hist<<<NBLK, 256, 0, stream>>>(dst, E, CHUNK, NBLK, NBUK, blockhist);
    k_bucket_scan<<<1, 512, 0, stream>>>(blockhist, bucketbase, NBLK, NBUK);
    k_colscan<<<NBUK, 256, 0, stream>>>(blockhist, bucketbase, NBLK);
    k_partition<<<NBLK, 256, 0, stream>>>(src, dst, E, CHUNK, NBLK, NBUK, blockhist, packed);
    k_fine<<<NBUK, 256, 0, stream>>>(packed, bucketbase, offsets, csr_src, N, NBUK);
    k_splitW2<<<12, 256, 0, stream>>>(W2, w2h, w2l);
    k_gemm1<<<gb, 256, 0, stream>>>(x, W1, as1, ad1, h1b, a_s1, a_d1, N);
    k_agg1<<<nb, 256, 0, stream>>>(h1b, a_s1, a_d1, offsets, csr_src, b1, y1, N);
    k_gemm2<<<gb, 256, 0, stream>>>(y1, w2h, w2l, as2, ad2, h2b, a2s, a2d, N);
    k_agg2<<<nb, 256, 0, stream>>>(h2b, a2s, a2d, offsets, csr_src, b2, out, N);
}

// Round 9
// 326.219 us; speedup vs baseline: 3.2449x; 1.0817x over previous
//
#include <hip/hip_runtime.h>
#include <math.h>

#define NEG_SLOPE 0.2f
#define BSHIFT 8            // 256 nodes per bucket
#define MAXBUK 512          // supports N up to 131072

typedef __attribute__((ext_vector_type(8))) short short8;   // 8 bf16 (MFMA A/B frag)
typedef __attribute__((ext_vector_type(4))) float floatx4;  // MFMA C/D frag

static __device__ __forceinline__ float lrelu_exp(float e) {
    e = fmaxf(e, NEG_SLOPE * e);
    return __expf(e);
}

// fp32 -> bf16 (round-to-nearest-even)
static __device__ __forceinline__ short f2bf(float f) {
    union { float f; unsigned u; } v; v.f = f;
    unsigned r = v.u + 0x7FFFu + ((v.u >> 16) & 1u);
    return (short)(r >> 16);
}
// bf16 bits -> fp32 (exact)
static __device__ __forceinline__ float bf2f(unsigned short s) {
    union { float f; unsigned u; } v;
    v.u = ((unsigned)s) << 16;
    return v.f;
}
// packed pair of bf16 -> two fp32 (1 shift / 1 and)
static __device__ __forceinline__ float bfpair_lo(unsigned v) {
    union { float f; unsigned u; } x; x.u = v << 16; return x.f;
}
static __device__ __forceinline__ float bfpair_hi(unsigned v) {
    union { float f; unsigned u; } x; x.u = v & 0xffff0000u; return x.f;
}
// split f into hi+lo bf16 pair (covers ~16 mantissa bits)
static __device__ __forceinline__ void splitbf(float f, short& hi, short& lo) {
    hi = f2bf(f);
    lo = f2bf(f - bf2f((unsigned short)hi));
}

// ================= CSR build: LDS-bucketed partition (no global data atomics) =================

__global__ __launch_bounds__(256) void k_hist(const int* __restrict__ dst, int E, int CHUNK,
                                              int NBLK, int NBUK, int* __restrict__ blockhist) {
    __shared__ int hist[MAXBUK];
    int t = threadIdx.x, b = blockIdx.x;
    for (int i = t; i < NBUK; i += 256) hist[i] = 0;
    __syncthreads();
    int e0 = b * CHUNK, e1 = e0 + CHUNK; if (e1 > E) e1 = E;
    for (int e = e0 + t; e < e1; e += 256) atomicAdd(&hist[dst[e] >> BSHIFT], 1);
    __syncthreads();
    for (int i = t; i < NBUK; i += 256) blockhist[i * NBLK + b] = hist[i];
}

__global__ __launch_bounds__(512) void k_bucket_scan(const int* __restrict__ blockhist,
                                                     int* __restrict__ bucketbase,
                                                     int NBLK, int NBUK) {
    __shared__ int sh[512];
    int t = threadIdx.x;
    int tot = 0;
    if (t < NBUK) {
        const int* p = blockhist + (size_t)t * NBLK;
        for (int k = 0; k < NBLK; ++k) tot += p[k];
    }
    sh[t] = tot;
    __syncthreads();
#pragma unroll
    for (int o = 1; o < 512; o <<= 1) {
        int u = (t >= o) ? sh[t - o] : 0;
        __syncthreads();
        sh[t] += u;
        __syncthreads();
    }
    if (t < NBUK) bucketbase[t] = sh[t] - tot;
    if (t == NBUK - 1) bucketbase[NBUK] = sh[t];
}

__global__ __launch_bounds__(256) void k_colscan(int* __restrict__ blockhist,
                                                 const int* __restrict__ bucketbase,
                                                 int NBLK) {
    int bucket = blockIdx.x, t = threadIdx.x;
    int v = (t < NBLK) ? blockhist[(size_t)bucket * NBLK + t] : 0;
    int lane = t & 63, wv = t >> 6;
    int s = v;
#pragma unroll
    for (int o = 1; o < 64; o <<= 1) {
        int u = __shfl_up(s, o, 64);
        if (lane >= o) s += u;
    }
    __shared__ int wsum[4];
    if (lane == 63) wsum[wv] = s;
    __syncthreads();
    int base = 0;
#pragma unroll
    for (int w = 0; w < 4; ++w) base += (w < wv) ? wsum[w] : 0;
    int excl = s + base - v + bucketbase[bucket];
    if (t < NBLK) blockhist[(size_t)bucket * NBLK + t] = excl;
}

// packed record: (src << 8) | (dst & 255)   [src < 2^24; bucket id recovers dst high bits]
__global__ __launch_bounds__(256) void k_partition(const int* __restrict__ src,
                                                   const int* __restrict__ dst, int E, int CHUNK,
                                                   int NBLK, int NBUK,
                                                   const int* __restrict__ blockhist,
                                                   unsigned* __restrict__ packed) {
    __shared__ int cur[MAXBUK];
    int t = threadIdx.x, b = blockIdx.x;
    for (int i = t; i < NBUK; i += 256) cur[i] = blockhist[(size_t)i * NBLK + b];
    __syncthreads();
    int e0 = b * CHUNK, e1 = e0 + CHUNK; if (e1 > E) e1 = E;
    for (int e = e0 + t; e < e1; e += 256) {
        int d = dst[e], s = src[e];
        int pos = atomicAdd(&cur[d >> BSHIFT], 1);
        packed[pos] = ((unsigned)s << 8) | ((unsigned)d & 255u);
    }
}

__global__ __launch_bounds__(256) void k_fine(const unsigned* __restrict__ packed,
                                              const int* __restrict__ bucketbase,
                                              int* __restrict__ offsets,
                                              int* __restrict__ csr_src,
                                              int N, int NBUK) {
    __shared__ int fcnt[256];
    __shared__ int wsum[4];
    int bucket = blockIdx.x, t = threadIdx.x;
    int lo = bucket << BSHIFT;
    int nn = N - lo; if (nn > 256) nn = 256;
    int ebase = bucketbase[bucket];
    int ecnt = bucketbase[bucket + 1] - ebase;
    fcnt[t] = 0;
    __syncthreads();
    for (int i = t; i < ecnt; i += 256) {
        unsigned p = packed[ebase + i];
        atomicAdd(&fcnt[p & 255u], 1);
    }
    __syncthreads();
    int v = fcnt[t];
    int lane = t & 63, wv = t >> 6;
    int s = v;
#pragma unroll
    for (int o = 1; o < 64; o <<= 1) {
        int u = __shfl_up(s, o, 64);
        if (lane >= o) s += u;
    }
    if (lane == 63) wsum[wv] = s;
    __syncthreads();
    int base = 0;
#pragma unroll
    for (int w = 0; w < 4; ++w) base += (w < wv) ? wsum[w] : 0;
    int excl = s + base - v;
    if (t < nn) offsets[lo + t] = ebase + excl;
    if (bucket == NBUK - 1 && t == 0) offsets[N] = ebase + ecnt;  // == E
    __syncthreads();
    fcnt[t] = excl;   // reuse as cursor
    __syncthreads();
    for (int i = t; i < ecnt; i += 256) {
        unsigned p = packed[ebase + i];
        int pos = atomicAdd(&fcnt[p & 255u], 1);
        csr_src[ebase + pos] = (int)(p >> 8);
    }
}

// ---------------- W2 pre-split: hi/lo bf16, padded 40 -> 48 cols ----------------
__global__ __launch_bounds__(256) void k_splitW2(const float* __restrict__ W2,
                                                 short* __restrict__ w2h,
                                                 short* __restrict__ w2l) {
    int i = blockIdx.x * 256 + threadIdx.x;
    if (i < 64 * 48) {
        int row = i / 48, col = i % 48;
        short hi = 0, lo = 0;
        if (col < 40) splitbf(W2[row * 40 + col], hi, lo);
        w2h[i] = hi; w2l[i] = lo;
    }
}

// ---------------- Layer 1 GEMM via MFMA bf16 (plain; inputs replay-constant) ----------------
__global__ __launch_bounds__(256) void k_gemm1(const float* __restrict__ x,
                                               const float* __restrict__ W1,
                                               const float* __restrict__ att_s,
                                               const float* __restrict__ att_d,
                                               unsigned short* __restrict__ h1b,
                                               float* __restrict__ a_s1,
                                               float* __restrict__ a_d1, int N) {
    int tid = threadIdx.x, wave = tid >> 6, lane = tid & 63;
    int n16 = lane & 15, q = lane >> 4;
    int nb = blockIdx.x * 64 + wave * 16;
    if (nb >= N) return;

    short8 bfr[4][4];
#pragma unroll
    for (int ct = 0; ct < 4; ++ct) {
        int n = ct * 16 + n16;
#pragma unroll
        for (int kc = 0; kc < 4; ++kc) {
            int k0 = kc * 32 + q * 8;
            short8 b;
#pragma unroll
            for (int j = 0; j < 8; ++j) b[j] = f2bf(W1[(k0 + j) * 64 + n]);
            bfr[ct][kc] = b;
        }
    }

    int arow = nb + n16; if (arow >= N) arow = N - 1;
    const float* xr = x + (size_t)arow * 128 + q * 8;
    short8 afr[4];
#pragma unroll
    for (int kc = 0; kc < 4; ++kc) {
        float4 u0 = *(const float4*)(xr + kc * 32);
        float4 u1 = *(const float4*)(xr + kc * 32 + 4);
        short8 a;
        a[0] = f2bf(u0.x); a[1] = f2bf(u0.y); a[2] = f2bf(u0.z); a[3] = f2bf(u0.w);
        a[4] = f2bf(u1.x); a[5] = f2bf(u1.y); a[6] = f2bf(u1.z); a[7] = f2bf(u1.w);
        afr[kc] = a;
    }

    floatx4 acc[4];
#pragma unroll
    for (int ct = 0; ct < 4; ++ct) {
        floatx4 c = {0.f, 0.f, 0.f, 0.f};
#pragma unroll
        for (int kc = 0; kc < 4; ++kc)
            c = __builtin_amdgcn_mfma_f32_16x16x32_bf16(afr[kc], bfr[ct][kc], c, 0, 0, 0);
        acc[ct] = c;
    }

#pragma unroll
    for (int ct = 0; ct < 4; ++ct) {
#pragma unroll
        for (int r = 0; r < 4; ++r) {
            int row = nb + q * 4 + r;
            if (row < N) h1b[(size_t)row * 64 + ct * 16 + n16] = (unsigned short)f2bf(acc[ct][r]);
        }
    }

#pragma unroll
    for (int ct = 0; ct < 4; ++ct) {
        float as = att_s[ct * 16 + n16];
        float ad = att_d[ct * 16 + n16];
#pragma unroll
        for (int r = 0; r < 4; ++r) {
            float ps = acc[ct][r] * as;
            float pd = acc[ct][r] * ad;
#pragma unroll
            for (int m = 1; m < 8; m <<= 1) {
                ps += __shfl_xor(ps, m, 64);
                pd += __shfl_xor(pd, m, 64);
            }
            int row = nb + q * 4 + r;
            if ((n16 & 7) == 0 && row < N) {
                int h = 2 * ct + (n16 >> 3);
                a_s1[row * 8 + h] = ps;
                a_d1[row * 8 + h] = pd;
            }
        }
    }
}

// ---------------- Layer 1 aggregation: 2 edges per gather instr, 16 edges in flight ----------
// lane = (q2, c): half q2 processes its own edge; c = channel pair (2c, 2c+1); head = c>>2.
__global__ __launch_bounds__(256) void k_agg1(const unsigned short* __restrict__ h1b,
                                              const float* __restrict__ a_s1,
                                              const float* __restrict__ a_d1,
                                              const int* __restrict__ offsets,
                                              const int* __restrict__ csr_src,
                                              const float* __restrict__ b1,
                                              float* __restrict__ y1, int N) {
    int wave = threadIdx.x >> 6, lane = threadIdx.x & 63;
    int d = blockIdx.x * 4 + wave;
    if (d >= N) return;
    int q2 = lane >> 5;          // which edge of the pair
    int c  = lane & 31;          // channel pair: 2c, 2c+1
    int h  = c >> 2;             // head (same for both channels)
    float ad = a_d1[d * 8 + h];
    float accx = 0.f, accy = 0.f;
    float wsum_l = 0.f;
    if (q2 == 0) {               // self-loop on half 0
        float w0 = lrelu_exp(a_s1[d * 8 + h] + ad);
        unsigned v = *(const unsigned*)(h1b + (size_t)d * 64 + 2 * c);
        accx = w0 * bfpair_lo(v);
        accy = w0 * bfpair_hi(v);
        wsum_l = w0;
    }
    int i0 = offsets[d], i1 = offsets[d + 1];
    for (int base = i0; base < i1; base += 64) {
        int m = i1 - base; if (m > 64) m = 64;
        int sv = (lane < m) ? csr_src[base + lane] : 0;
        for (int j = 0; j < m; j += 16) {
            int   ei[8]; int si[8]; float ev[8]; unsigned vv[8];
#pragma unroll
            for (int u = 0; u < 8; ++u) {
                ei[u] = j + 2 * u + q2;
                si[u] = __shfl(sv, ei[u], 64);
            }
#pragma unroll
            for (int u = 0; u < 8; ++u) ev[u] = a_s1[si[u] * 8 + h] + ad;
#pragma unroll
            for (int u = 0; u < 8; ++u)
                vv[u] = *(const unsigned*)(h1b + (size_t)si[u] * 64 + 2 * c);
#pragma unroll
            for (int u = 0; u < 8; ++u) {
                float w = (ei[u] < m) ? lrelu_exp(ev[u]) : 0.f;
                wsum_l += w;
                accx = fmaf(w, bfpair_lo(vv[u]), accx);
                accy = fmaf(w, bfpair_hi(vv[u]), accy);
            }
        }
    }
    // combine the two halves (edges were split across halves; channels identical)
    accx += __shfl_xor(accx, 32, 64);
    accy += __shfl_xor(accy, 32, 64);
    wsum_l += __shfl_xor(wsum_l, 32, 64);
    if (q2 == 0) {
        float inv = 1.f / (wsum_l + 1e-16f);
        float bx = b1[2 * c], by = b1[2 * c + 1];
        float ox = accx * inv + bx;
        float oy = accy * inv + by;
        ox = ox > 0.f ? ox : expm1f(ox);
        oy = oy > 0.f ? oy : expm1f(oy);
        float2 o2 = make_float2(ox, oy);
        *(float2*)(y1 + (size_t)d * 64 + 2 * c) = o2;   // fp32 (precision-critical)
    }
}

// ---------------- Layer 2 GEMM, split-bf16 (y1 replay-variant -> fp32-class needed) ----------
__global__ __launch_bounds__(256) void k_gemm2(const float* __restrict__ y1,
                                               const short* __restrict__ w2h,
                                               const short* __restrict__ w2l,
                                               const float* __restrict__ att_s,
                                               const float* __restrict__ att_d,
                                               unsigned short* __restrict__ h2b,
                                               float* __restrict__ a2s,
                                               float* __restrict__ a2d, int N) {
    int tid = threadIdx.x, wave = tid >> 6, lane = tid & 63;
    int n16 = lane & 15, q = lane >> 4;
    int nb = blockIdx.x * 64 + wave * 16;
    if (nb >= N) return;

    int arow = nb + n16; if (arow >= N) arow = N - 1;
    const float* yr = y1 + (size_t)arow * 64 + q * 8;
    short8 ah[2], al[2];
#pragma unroll
    for (int kc = 0; kc < 2; ++kc) {
        float4 u0 = *(const float4*)(yr + kc * 32);
        float4 u1 = *(const float4*)(yr + kc * 32 + 4);
        short8 h, l; short hi, lo;
        splitbf(u0.x, hi, lo); h[0] = hi; l[0] = lo;
        splitbf(u0.y, hi, lo); h[1] = hi; l[1] = lo;
        splitbf(u0.z, hi, lo); h[2] = hi; l[2] = lo;
        splitbf(u0.w, hi, lo); h[3] = hi; l[3] = lo;
        splitbf(u1.x, hi, lo); h[4] = hi; l[4] = lo;
        splitbf(u1.y, hi, lo); h[5] = hi; l[5] = lo;
        splitbf(u1.z, hi, lo); h[6] = hi; l[6] = lo;
        splitbf(u1.w, hi, lo); h[7] = hi; l[7] = lo;
        ah[kc] = h; al[kc] = l;
    }

    float psr[4] = {0.f, 0.f, 0.f, 0.f}, pdr[4] = {0.f, 0.f, 0.f, 0.f};
#pragma unroll
    for (int ct = 0; ct < 3; ++ct) {
        int n = ct * 16 + n16;
        short8 bh0, bh1, bl0, bl1;
#pragma unroll
        for (int j = 0; j < 8; ++j) {
            int k0 = q * 8 + j;
            bh0[j] = w2h[k0 * 48 + n];
            bl0[j] = w2l[k0 * 48 + n];
            bh1[j] = w2h[(32 + k0) * 48 + n];
            bl1[j] = w2l[(32 + k0) * 48 + n];
        }
        floatx4 c = {0.f, 0.f, 0.f, 0.f};
        c = __builtin_amdgcn_mfma_f32_16x16x32_bf16(ah[0], bl0, c, 0, 0, 0);
        c = __builtin_amdgcn_mfma_f32_16x16x32_bf16(al[0], bh0, c, 0, 0, 0);
        c = __builtin_amdgcn_mfma_f32_16x16x32_bf16(ah[0], bh0, c, 0, 0, 0);
        c = __builtin_amdgcn_mfma_f32_16x16x32_bf16(ah[1], bl1, c, 0, 0, 0);
        c = __builtin_amdgcn_mfma_f32_16x16x32_bf16(al[1], bh1, c, 0, 0, 0);
        c = __builtin_amdgcn_mfma_f32_16x16x32_bf16(ah[1], bh1, c, 0, 0, 0);

        int col = ct * 16 + n16;
#pragma unroll
        for (int r = 0; r < 4; ++r) {
            int row = nb + q * 4 + r;
            if (col < 40 && row < N) h2b[(size_t)row * 40 + col] = (unsigned short)f2bf(c[r]);
        }
        float asv = (col < 40) ? att_s[col] : 0.f;
        float adv = (col < 40) ? att_d[col] : 0.f;
#pragma unroll
        for (int r = 0; r < 4; ++r) {
            psr[r] = fmaf(c[r], asv, psr[r]);
            pdr[r] = fmaf(c[r], adv, pdr[r]);
        }
    }
#pragma unroll
    for (int r = 0; r < 4; ++r) {
        float ps = psr[r], pd = pdr[r];
#pragma unroll
        for (int m = 1; m < 16; m <<= 1) {
            ps += __shfl_xor(ps, m, 64);
            pd += __shfl_xor(pd, m, 64);
        }
        int row = nb + q * 4 + r;
        if (n16 == 0 && row < N) { a2s[row] = ps; a2d[row] = pd; }
    }
}

// ---------------- Layer 2 aggregation: 3 edges per gather instr + log_softmax ----------------
// lane = (t, c): third t processes its own edge; c = channel pair (2c, 2c+1), c < 20.
__global__ __launch_bounds__(256) void k_agg2(const unsigned short* __restrict__ h2b,
                                              const float* __restrict__ a2s,
                                              const float* __restrict__ a2d,
                                              const int* __restrict__ offsets,
                                              const int* __restrict__ csr_src,
                                              const float* __restrict__ b2,
                                              float* __restrict__ out, int N) {
    int wave = threadIdx.x >> 6, lane = threadIdx.x & 63;
    int d = blockIdx.x * 4 + wave;
    if (d >= N) return;
    int t = lane / 20;          // 0..2 active thirds (3 = idle tail lanes 60..63)
    int c = lane % 20;          // channel pair: 2c, 2c+1
    float ad = a2d[d];
    float w0 = lrelu_exp(a2s[d] + ad);
    float accx = 0.f, accy = 0.f;
    if (t == 0) {               // self-loop on third 0
        unsigned v = *(const unsigned*)(h2b + (size_t)d * 40 + 2 * c);
        accx = w0 * bfpair_lo(v);
        accy = w0 * bfpair_hi(v);
    }
    float wsum_l = 0.f;
    int i0 = offsets[d], i1 = offsets[d + 1];
    for (int base = i0; base < i1; base += 48) {
        int m = i1 - base; if (m > 48) m = 48;
        int sv = 0; float wv = 0.f;
        if (lane < m) {                       // m <= 48 so only lanes 0..47 load
            sv = csr_src[base + lane];
            wv = lrelu_exp(a2s[sv] + ad);
        }
        wsum_l += wv;
        for (int j = 0; j < m; j += 24) {
            int si[8]; float wq[8]; unsigned vv[8];
#pragma unroll
            for (int u = 0; u < 8; ++u) {
                int e = j + 3 * u + t;        // e <= 45+21+3 = 48 < 64, lane 48.. has wv=0
                si[u] = __shfl(sv, e, 64);
                wq[u] = __shfl(wv, e, 64);
            }
#pragma unroll
            for (int u = 0; u < 8; ++u)
                vv[u] = *(const unsigned*)(h2b + (size_t)si[u] * 40 + 2 * c);
#pragma unroll
            for (int u = 0; u < 8; ++u) {
                accx = fmaf(wq[u], bfpair_lo(vv[u]), accx);
                accy = fmaf(wq[u], bfpair_hi(vv[u]), accy);
            }
        }
    }
    // combine the three thirds into t==0 lanes
    accx += __shfl(accx, lane + 20, 64) + __shfl(accx, lane + 40, 64);
    accy += __shfl(accy, lane + 20, 64) + __shfl(accy, lane + 40, 64);
#pragma unroll
    for (int mm = 1; mm < 64; mm <<= 1) wsum_l += __shfl_xor(wsum_l, mm, 64);
    float wsum = wsum_l + w0;
    bool act = (lane < 20);
    float inv = 1.f / (wsum + 1e-16f);
    float ox = act ? (accx * inv + b2[2 * c]) : -INFINITY;
    float oy = act ? (accy * inv + b2[2 * c + 1]) : -INFINITY;
    float mx = fmaxf(ox, oy);
#pragma unroll
    for (int mm = 1; mm < 64; mm <<= 1) mx = fmaxf(mx, __shfl_xor(mx, mm, 64));
    float ex = act ? (__expf(ox - mx) + __expf(oy - mx)) : 0.f;
#pragma unroll
    for (int mm = 1; mm < 64; mm <<= 1) ex += __shfl_xor(ex, mm, 64);
    if (act) {
        float lse = __logf(ex);
        float2 o2 = make_float2(ox - mx - lse, oy - mx - lse);
        *(float2*)(out + (size_t)d * 40 + 2 * c) = o2;
    }
}

// ---------------- launcher ----------------

extern "C" void kernel_launch(void* const* d_in, const int* in_sizes, int n_in,
                              void* d_out, int out_size, void* d_ws, size_t ws_size,
                              hipStream_t stream) {
    const float* x   = (const float*)d_in[0];
    const int*   ei  = (const int*)d_in[1];
    const float* W1  = (const float*)d_in[2];
    const float* as1 = (const float*)d_in[3];
    const float* ad1 = (const float*)d_in[4];
    const float* b1  = (const float*)d_in[5];
    const float* W2  = (const float*)d_in[6];
    const float* as2 = (const float*)d_in[7];
    const float* ad2 = (const float*)d_in[8];
    const float* b2  = (const float*)d_in[9];
    float* out = (float*)d_out;

    int N = in_sizes[0] / 128;   // 100000
    int E = in_sizes[1] / 2;     // 1600000
    const int* src = ei;
    const int* dst = ei + E;

    int NBUK = (N + 255) >> BSHIFT;          // 391
    int CHUNK = 8192;
    while ((E + CHUNK - 1) / CHUNK > 256) CHUNK <<= 1;
    int NBLK = (E + CHUNK - 1) / CHUNK;      // 196

    char* ws = (char*)d_ws;
    size_t off = 0;
    auto alloc = [&](size_t bytes) -> char* {
        char* p = ws + off;
        off += (bytes + 255) & ~(size_t)255;
        return p;
    };
    unsigned short* h1b = (unsigned short*)alloc((size_t)N * 64 * 2);   // bf16
    float* a_s1    = (float*)alloc((size_t)N * 8 * 4);
    float* a_d1    = (float*)alloc((size_t)N * 8 * 4);
    float* y1      = (float*)alloc((size_t)N * 64 * 4);                 // fp32 (precision-critical)
    // h2b (bf16, 8 MB) and packed (uint, 6.4 MB) are temporally disjoint: share region.
    size_t shared_sz = (size_t)N * 40 * 2;
    if ((size_t)E * 4 > shared_sz) shared_sz = (size_t)E * 4;
    char*  region  = alloc(shared_sz);
    unsigned short* h2b = (unsigned short*)region;
    unsigned* packed    = (unsigned*)region;
    float* a2s     = (float*)alloc((size_t)N * 4);
    float* a2d     = (float*)alloc((size_t)N * 4);
    int*   offsets = (int*)alloc((size_t)(N + 1) * 4);
    int*   csr_src = (int*)alloc((size_t)E * 4);
    int*   blockhist  = (int*)alloc((size_t)NBUK * NBLK * 4);
    int*   bucketbase = (int*)alloc((size_t)(NBUK + 1) * 4);
    short* w2h     = (short*)alloc((size_t)64 * 48 * 2);
    short* w2l     = (short*)alloc((size_t)64 * 48 * 2);

    int nb = (N + 3) / 4;
    int gb = (N + 63) / 64;

    k_hist<<<NBLK, 256, 0, stream>>>(dst, E, CHUNK, NBLK, NBUK, blockhist);
    k_bucket_scan<<<1, 512, 0, stream>>>(blockhist, bucketbase, NBLK, NBUK);
    k_colscan<<<NBUK, 256, 0, stream>>>(blockhist, bucketbase, NBLK);
    k_partition<<<NBLK, 256, 0, stream>>>(src, dst, E, CHUNK, NBLK, NBUK, blockhist, packed);
    k_fine<<<NBUK, 256, 0, stream>>>(packed, bucketbase, offsets, csr_src, N, NBUK);
    k_splitW2<<<12, 256, 0, stream>>>(W2, w2h, w2l);
    k_gemm1<<<gb, 256, 0, stream>>>(x, W1, as1, ad1, h1b, a_s1, a_d1, N);
    k_agg1<<<nb, 256, 0, stream>>>(h1b, a_s1, a_d1, offsets, csr_src, b1, y1, N);
    k_gemm2<<<gb, 256, 0, stream>>>(y1, w2h, w2l, as2, ad2, h2b, a2s, a2d, N);
    k_agg2<<<nb, 256, 0, stream>>>(h2b, a2s, a2d, offsets, csr_src, b2, out, N);
}